// Round 1
// baseline (1128.737 us; speedup 1.0000x reference)
//
#include <hip/hip_runtime.h>

// Problem constants (fixed by the reference): in_c=5, hid=128, out_c=64
#define IN_C 5
#define HID  128
#define OUTC 64

// ---------------- kernels ----------------

__global__ void k_deg_init(float* __restrict__ deg, int n) {
    int i = blockIdx.x * blockDim.x + threadIdx.x;
    if (i < n) deg[i] = 1.0f;  // self-loop
}

__global__ void k_deg_count(const int* __restrict__ dst, float* __restrict__ deg, int E) {
    int e = blockIdx.x * blockDim.x + threadIdx.x;
    if (e < E) atomicAdd(&deg[dst[e]], 1.0f);
}

__global__ void k_dinv(float* __restrict__ deg, int n) {
    int i = blockIdx.x * blockDim.x + threadIdx.x;
    if (i < n) deg[i] = rsqrtf(deg[i]);  // deg >= 1 always (self-loop)
}

// xagg[v] = x[v] * dinv[v]   (self-loop term; also the per-source scaled features)
__global__ void k_xagg_init(const float* __restrict__ x, const float* __restrict__ dinv,
                            float* __restrict__ xagg, int n) {
    int i = blockIdx.x * blockDim.x + threadIdx.x;
    if (i < n * IN_C) {
        int v = i / IN_C;
        xagg[i] = x[i] * dinv[v];
    }
}

// xagg[d] += x[s]*dinv[s]  for every edge (5 atomics per edge)
__global__ void k_scatter5(const int* __restrict__ src, const int* __restrict__ dst,
                           const float* __restrict__ x, const float* __restrict__ dinv,
                           float* __restrict__ xagg, int E) {
    int e = blockIdx.x * blockDim.x + threadIdx.x;
    if (e < E) {
        int s = src[e];
        int d = dst[e];
        float ds = dinv[s];
        const float* xs = x + (size_t)s * IN_C;
        float* xd = xagg + (size_t)d * IN_C;
#pragma unroll
        for (int c = 0; c < IN_C; ++c)
            atomicAdd(&xd[c], xs[c] * ds);
    }
}

// h1[v,j] = relu(dinv[v] * dot(xagg[v,:], W1[:,j]) + b1[j])
// 256 threads = 2 nodes x 128 outputs
__global__ void k_gemm1_relu(const float* __restrict__ xagg, const float* __restrict__ dinv,
                             const float* __restrict__ W1, const float* __restrict__ b1,
                             float* __restrict__ h1, int n) {
    int t = threadIdx.x;
    int v = blockIdx.x * 2 + (t >> 7);  // t/128
    int j = t & (HID - 1);
    if (v < n) {
        const float* xv = xagg + (size_t)v * IN_C;
        float acc = 0.0f;
#pragma unroll
        for (int k = 0; k < IN_C; ++k)
            acc += xv[k] * W1[k * HID + j];
        float val = acc * dinv[v] + b1[j];
        h1[(size_t)v * HID + j] = fmaxf(val, 0.0f);
    }
}

// g2[v,j] = dinv[v] * dot(h1[v,:], W2[:,j]);  also d_out[v,j] = g2[v,j] (self-loop init)
// 256 threads = 4 nodes x 64 outputs
__global__ void k_gemm2(const float* __restrict__ h1, const float* __restrict__ dinv,
                        const float* __restrict__ W2, float* __restrict__ g2,
                        float* __restrict__ out, int n) {
    int t = threadIdx.x;
    int v = blockIdx.x * 4 + (t >> 6);
    int j = t & (OUTC - 1);
    if (v < n) {
        const float* hv = h1 + (size_t)v * HID;
        float acc = 0.0f;
#pragma unroll 8
        for (int k = 0; k < HID; ++k)
            acc += hv[k] * W2[k * OUTC + j];
        float val = acc * dinv[v];
        size_t o = (size_t)v * OUTC + j;
        g2[o] = val;
        out[o] = val;
    }
}

// d_out[d,:] += g2[s,:]  -- one 64-lane wave per edge, lane c handles feature c
__global__ void k_scatter64(const int* __restrict__ src, const int* __restrict__ dst,
                            const float* __restrict__ g2, float* __restrict__ out, int E) {
    int gid = blockIdx.x * blockDim.x + threadIdx.x;
    int e = gid >> 6;        // gid / 64
    int c = gid & 63;
    if (e < E) {
        int s = src[e];
        int d = dst[e];
        atomicAdd(&out[(size_t)d * OUTC + c], g2[(size_t)s * OUTC + c]);
    }
}

// out[v,j] = dinv[v]*out[v,j] + b2[j]
__global__ void k_finalize(float* __restrict__ out, const float* __restrict__ dinv,
                           const float* __restrict__ b2, int n) {
    int i = blockIdx.x * blockDim.x + threadIdx.x;
    if (i < n * OUTC) {
        int v = i >> 6;
        int j = i & (OUTC - 1);
        out[i] = dinv[v] * out[i] + b2[j];
    }
}

// ---------------- launch ----------------

extern "C" void kernel_launch(void* const* d_in, const int* in_sizes, int n_in,
                              void* d_out, int out_size, void* d_ws, size_t ws_size,
                              hipStream_t stream) {
    const float* x    = (const float*)d_in[0];
    const int*   ei   = (const int*)d_in[1];
    const float* W1   = (const float*)d_in[2];
    const float* b1   = (const float*)d_in[3];
    const float* W2   = (const float*)d_in[4];
    const float* b2   = (const float*)d_in[5];
    float*       out  = (float*)d_out;

    const int n = in_sizes[0] / IN_C;      // 100000
    const int E = in_sizes[1] / 2;         // 1600000
    const int* src = ei;
    const int* dst = ei + E;

    // workspace layout (floats), all offsets 16B-aligned
    char* ws = (char*)d_ws;
    float* dinv = (float*)ws;                                  // n
    float* xagg = (float*)(ws + (size_t)n * 4);                // n*IN_C
    float* h1   = (float*)(ws + (size_t)n * 4 * (1 + IN_C));   // n*HID
    float* g2   = (float*)(ws + (size_t)n * 4 * (1 + IN_C + HID)); // n*OUTC

    const int B = 256;

    // degrees -> dinv
    k_deg_init<<<(n + B - 1) / B, B, 0, stream>>>(dinv, n);
    k_deg_count<<<(E + B - 1) / B, B, 0, stream>>>(dst, dinv, E);
    k_dinv<<<(n + B - 1) / B, B, 0, stream>>>(dinv, n);

    // layer 1: aggregate in 5-dim input space, then GEMM + relu
    k_xagg_init<<<(n * IN_C + B - 1) / B, B, 0, stream>>>(x, dinv, xagg, n);
    k_scatter5<<<(E + B - 1) / B, B, 0, stream>>>(src, dst, x, dinv, xagg, E);
    k_gemm1_relu<<<(n + 1) / 2, B, 0, stream>>>(xagg, dinv, W1, b1, h1, n);

    // layer 2: GEMM (+row scale), scatter in 64-dim output space, finalize
    k_gemm2<<<(n + 3) / 4, B, 0, stream>>>(h1, dinv, W2, g2, out, n);
    {
        long long total = (long long)E * OUTC;
        int grid = (int)((total + B - 1) / B);
        k_scatter64<<<grid, B, 0, stream>>>(src, dst, g2, out, E);
    }
    k_finalize<<<(n * OUTC + B - 1) / B, B, 0, stream>>>(out, dinv, b2, n);
}

// Round 2
// 655.131 us; speedup vs baseline: 1.7229x; 1.7229x over previous
//
#include <hip/hip_runtime.h>

#define IN_C 5
#define HID  128
#define OUTC 64

// ---------------- CSR build ----------------

__global__ void k_zero_int(int* __restrict__ p, int n) {
    int i = blockIdx.x * blockDim.x + threadIdx.x;
    if (i < n) p[i] = 0;
}

__global__ void k_hist(const int* __restrict__ dst, int* __restrict__ cnt, int E) {
    int e = blockIdx.x * blockDim.x + threadIdx.x;
    if (e < E) atomicAdd(&cnt[dst[e]], 1);
}

// per-1024-block exclusive scan of cnt -> rowptr, block totals -> blocksums
__global__ void k_scan_block(const int* __restrict__ cnt, int* __restrict__ rowptr,
                             int* __restrict__ blocksums, int n) {
    __shared__ int sh[1024];
    int i = blockIdx.x * 1024 + threadIdx.x;
    int v = (i < n) ? cnt[i] : 0;
    sh[threadIdx.x] = v;
    __syncthreads();
    for (int off = 1; off < 1024; off <<= 1) {
        int add = (threadIdx.x >= off) ? sh[threadIdx.x - off] : 0;
        __syncthreads();
        sh[threadIdx.x] += add;
        __syncthreads();
    }
    if (i < n) rowptr[i] = sh[threadIdx.x] - v;  // exclusive within block
    if (threadIdx.x == 1023) blocksums[blockIdx.x] = sh[1023];
}

// serial exclusive scan of block sums (nb ~ 98, trivial)
__global__ void k_scan_sums(int* __restrict__ blocksums, int nb) {
    if (threadIdx.x == 0 && blockIdx.x == 0) {
        int acc = 0;
        for (int i = 0; i < nb; ++i) {
            int v = blocksums[i];
            blocksums[i] = acc;
            acc += v;
        }
    }
}

// add block offsets; init cursor copy; compute dinv = rsqrt(1+deg)
__global__ void k_scan_add(int* __restrict__ rowptr, const int* __restrict__ blocksums,
                           int* __restrict__ cursor, const int* __restrict__ cnt,
                           float* __restrict__ dinv, int n) {
    int i = blockIdx.x * blockDim.x + threadIdx.x;
    if (i < n) {
        int r = rowptr[i] + blocksums[i >> 10];
        rowptr[i] = r;
        cursor[i] = r;
        dinv[i] = rsqrtf(1.0f + (float)cnt[i]);
    }
}

__global__ void k_fill(const int* __restrict__ src, const int* __restrict__ dst,
                       int* __restrict__ cursor, int* __restrict__ col, int E) {
    int e = blockIdx.x * blockDim.x + threadIdx.x;
    if (e < E) {
        int d = dst[e];
        int p = atomicAdd(&cursor[d], 1);
        col[p] = src[e];
    }
}

// ---------------- layer 1 ----------------

// xagg[v,c] = x[v,c]*dinv[v] + sum_{s in N(v)} x[s,c]*dinv[s]
// one thread per (v,c): i = v*5+c
__global__ void k_agg1(const float* __restrict__ x, const float* __restrict__ dinv,
                       const int* __restrict__ rowptr, const int* __restrict__ cnt,
                       const int* __restrict__ col, float* __restrict__ xagg, int n) {
    int i = blockIdx.x * blockDim.x + threadIdx.x;
    if (i < n * IN_C) {
        int v = i / IN_C;
        int c = i - v * IN_C;
        float acc = x[i] * dinv[v];
        int start = rowptr[v];
        int len = cnt[v];
        for (int k = 0; k < len; ++k) {
            int s = col[start + k];
            acc += x[(size_t)s * IN_C + c] * dinv[s];
        }
        xagg[i] = acc;
    }
}

// h1[v,j] = relu(dinv[v]*dot(xagg[v,:],W1[:,j]) + b1[j]); 2 nodes/block
__global__ void k_gemm1_relu(const float* __restrict__ xagg, const float* __restrict__ dinv,
                             const float* __restrict__ W1, const float* __restrict__ b1,
                             float* __restrict__ h1, int n) {
    int t = threadIdx.x;
    int v = blockIdx.x * 2 + (t >> 7);
    int j = t & (HID - 1);
    if (v < n) {
        const float* xv = xagg + (size_t)v * IN_C;
        float acc = 0.0f;
#pragma unroll
        for (int k = 0; k < IN_C; ++k)
            acc += xv[k] * W1[k * HID + j];
        float val = acc * dinv[v] + b1[j];
        h1[(size_t)v * HID + j] = fmaxf(val, 0.0f);
    }
}

// ---------------- layer 2 ----------------

// g2[v,j] = dinv[v] * dot(h1[v,:], W2[:,j]); 4 nodes/block
__global__ void k_gemm2(const float* __restrict__ h1, const float* __restrict__ dinv,
                        const float* __restrict__ W2, float* __restrict__ g2, int n) {
    int t = threadIdx.x;
    int v = blockIdx.x * 4 + (t >> 6);
    int j = t & (OUTC - 1);
    if (v < n) {
        const float* hv = h1 + (size_t)v * HID;
        float acc = 0.0f;
#pragma unroll 8
        for (int k = 0; k < HID; ++k)
            acc += hv[k] * W2[k * OUTC + j];
        g2[(size_t)v * OUTC + j] = acc * dinv[v];
    }
}

// out[v,c] = dinv[v]*(g2[v,c] + sum_{s in N(v)} g2[s,c]) + b2[c]
// one wave per node (lane = feature), 4 waves per block
__global__ void k_agg2(const float* __restrict__ g2, const float* __restrict__ dinv,
                       const int* __restrict__ rowptr, const int* __restrict__ cnt,
                       const int* __restrict__ col, const float* __restrict__ b2,
                       float* __restrict__ out, int n) {
    int t = threadIdx.x;
    int v = blockIdx.x * 4 + (t >> 6);
    int c = t & 63;
    if (v < n) {
        float acc = g2[(size_t)v * OUTC + c];
        int start = rowptr[v];
        int len = cnt[v];
        for (int k = 0; k < len; ++k) {
            int s = col[start + k];   // wave-uniform per iteration within lane group
            acc += g2[(size_t)s * OUTC + c];
        }
        out[(size_t)v * OUTC + c] = dinv[v] * acc + b2[c];
    }
}

// ---------------- launch ----------------

extern "C" void kernel_launch(void* const* d_in, const int* in_sizes, int n_in,
                              void* d_out, int out_size, void* d_ws, size_t ws_size,
                              hipStream_t stream) {
    const float* x  = (const float*)d_in[0];
    const int*   ei = (const int*)d_in[1];
    const float* W1 = (const float*)d_in[2];
    const float* b1 = (const float*)d_in[3];
    const float* W2 = (const float*)d_in[4];
    const float* b2 = (const float*)d_in[5];
    float*       out = (float*)d_out;

    const int n = in_sizes[0] / IN_C;   // 100000
    const int E = in_sizes[1] / 2;      // 1600000
    const int* src = ei;
    const int* dst = ei + E;

    // workspace layout
    char* ws = (char*)d_ws;
    size_t off = 0;
    int* cnt      = (int*)(ws + off); off += (size_t)n * 4;
    int* rowptr   = (int*)(ws + off); off += (size_t)n * 4;
    int* cursor   = (int*)(ws + off); off += (size_t)n * 4;
    int* blocksums= (int*)(ws + off); off += 1024 * 4;
    int* col      = (int*)(ws + off); off += (size_t)E * 4;
    float* dinv   = (float*)(ws + off); off += (size_t)n * 4;
    float* xagg   = (float*)(ws + off); off += (size_t)n * IN_C * 4;
    float* h1     = (float*)(ws + off); off += (size_t)n * HID * 4;
    float* g2     = (float*)(ws + off); off += (size_t)n * OUTC * 4;

    const int B = 256;
    const int nb_scan = (n + 1023) / 1024;

    // CSR build + dinv
    k_zero_int<<<(n + B - 1) / B, B, 0, stream>>>(cnt, n);
    k_hist<<<(E + B - 1) / B, B, 0, stream>>>(dst, cnt, E);
    k_scan_block<<<nb_scan, 1024, 0, stream>>>(cnt, rowptr, blocksums, n);
    k_scan_sums<<<1, 64, 0, stream>>>(blocksums, nb_scan);
    k_scan_add<<<(n + B - 1) / B, B, 0, stream>>>(rowptr, blocksums, cursor, cnt, dinv, n);
    k_fill<<<(E + B - 1) / B, B, 0, stream>>>(src, dst, cursor, col, E);

    // layer 1
    k_agg1<<<(n * IN_C + B - 1) / B, B, 0, stream>>>(x, dinv, rowptr, cnt, col, xagg, n);
    k_gemm1_relu<<<(n + 1) / 2, B, 0, stream>>>(xagg, dinv, W1, b1, h1, n);

    // layer 2
    k_gemm2<<<(n + 3) / 4, B, 0, stream>>>(h1, dinv, W2, g2, n);
    k_agg2<<<(n + 3) / 4, B, 0, stream>>>(g2, dinv, rowptr, cnt, col, b2, out, n);
}

// Round 3
// 402.591 us; speedup vs baseline: 2.8037x; 1.6273x over previous
//
#include <hip/hip_runtime.h>

#define IN_C 5
#define HID  128
#define OUTC 64

// ---------------- CSR build ----------------

__global__ void k_hist(const int* __restrict__ dst, int* __restrict__ cnt, int E) {
    int e = blockIdx.x * blockDim.x + threadIdx.x;
    if (e < E) atomicAdd(&cnt[dst[e]], 1);
}

// per-1024-block inclusive scan -> exclusive rowptr, block totals -> blocksums
__global__ void k_scan_block(const int* __restrict__ cnt, int* __restrict__ rowptr,
                             int* __restrict__ blocksums, int n) {
    __shared__ int sh[1024];
    int i = blockIdx.x * 1024 + threadIdx.x;
    int v = (i < n) ? cnt[i] : 0;
    sh[threadIdx.x] = v;
    __syncthreads();
    for (int off = 1; off < 1024; off <<= 1) {
        int add = (threadIdx.x >= off) ? sh[threadIdx.x - off] : 0;
        __syncthreads();
        sh[threadIdx.x] += add;
        __syncthreads();
    }
    if (i < n) rowptr[i] = sh[threadIdx.x] - v;
    if (threadIdx.x == 1023) blocksums[blockIdx.x] = sh[1023];
}

__global__ void k_scan_sums(int* __restrict__ blocksums, int nb) {
    if (threadIdx.x == 0 && blockIdx.x == 0) {
        int acc = 0;
        for (int i = 0; i < nb; ++i) { int v = blocksums[i]; blocksums[i] = acc; acc += v; }
    }
}

// finalize rowptr, cursor, dinv; also pre-scale x by dinv into padded xs[v][8]
__global__ void k_scan_add(int* __restrict__ rowptr, const int* __restrict__ blocksums,
                           int* __restrict__ cursor, const int* __restrict__ cnt,
                           const float* __restrict__ x, float* __restrict__ dinv,
                           float* __restrict__ xs, int n) {
    int i = blockIdx.x * blockDim.x + threadIdx.x;
    if (i < n) {
        int r = rowptr[i] + blocksums[i >> 10];
        rowptr[i] = r;
        cursor[i] = r;
        float dv = rsqrtf(1.0f + (float)cnt[i]);
        dinv[i] = dv;
        const float* xp = x + (size_t)i * IN_C;
        float4* o = (float4*)(xs + (size_t)i * 8);
        o[0] = make_float4(xp[0] * dv, xp[1] * dv, xp[2] * dv, xp[3] * dv);
        o[1] = make_float4(xp[4] * dv, 0.f, 0.f, 0.f);
    }
}

__global__ void k_fill(const int* __restrict__ src, const int* __restrict__ dst,
                       int* __restrict__ cursor, int* __restrict__ col, int E) {
    int e = blockIdx.x * blockDim.x + threadIdx.x;
    if (e < E) {
        int d = dst[e];
        int p = atomicAdd(&cursor[d], 1);
        col[p] = src[e];
    }
}

// ---------------- layer 1 aggregation (5-dim, padded to 8) ----------------
// xagg8[v] = xs[v] + sum_{s in N(v)} xs[s]   (dinv pre-folded into xs)
// 2 threads per node, each owns one float4 half
__global__ void k_agg1(const float* __restrict__ xs, const int* __restrict__ rowptr,
                       const int* __restrict__ cnt, const int* __restrict__ col,
                       float* __restrict__ xagg8, int n) {
    int i = blockIdx.x * blockDim.x + threadIdx.x;
    int v = i >> 1, half = (i & 1) * 4;
    if (v < n) {
        float4 acc = *(const float4*)(xs + (size_t)v * 8 + half);
        int start = rowptr[v], len = cnt[v];
        for (int k = 0; k < len; ++k) {
            int s = col[start + k];
            float4 t = *(const float4*)(xs + (size_t)s * 8 + half);
            acc.x += t.x; acc.y += t.y; acc.z += t.z; acc.w += t.w;
        }
        *(float4*)(xagg8 + (size_t)v * 8 + half) = acc;
    }
}

// ---------------- fused gemm1+relu+gemm2 ----------------
// Per block: 64 nodes. Phase A: h1t[j][v] in LDS (v = lane -> conflict-free).
// Phase B: register-tiled 4x4 SGEMM, W2 streamed from global (L1-resident 32KB).
#define NB 64
__global__ void __launch_bounds__(256, 4)
k_fused(const float* __restrict__ xagg8, const float* __restrict__ dinv,
        const float* __restrict__ W1, const float* __restrict__ b1,
        const float* __restrict__ W2, float* __restrict__ g2, int n) {
    __shared__ float sh_h1t[HID * NB];     // 32 KB, [j][v]
    __shared__ float sh_xa[NB * 9];        // padded stride 9
    __shared__ float sh_dinv[NB];
    int t = threadIdx.x;
    int base = blockIdx.x * NB;

    if (t < NB) {
        int v = base + t;
        float4 a = make_float4(0.f, 0.f, 0.f, 0.f), b = a;
        float dv = 0.f;
        if (v < n) {
            const float4* p = (const float4*)(xagg8 + (size_t)v * 8);
            a = p[0]; b = p[1];
            dv = dinv[v];
        }
        float* sx = sh_xa + t * 9;
        sx[0] = a.x; sx[1] = a.y; sx[2] = a.z; sx[3] = a.w; sx[4] = b.x;
        sh_dinv[t] = dv;
    }
    __syncthreads();

    // Phase A: h1t: 64 nodes x 128 j / 256 threads = 32 iters
    for (int p = 0; p < 32; ++p) {
        int idx = p * 256 + t;
        int v = idx & 63;        // per-lane
        int j = idx >> 6;        // wave-uniform
        const float* xa = sh_xa + v * 9;
        float acc = 0.f;
#pragma unroll
        for (int k = 0; k < IN_C; ++k)
            acc += xa[k] * W1[k * HID + j];
        float h = fmaxf(acc * sh_dinv[v] + b1[j], 0.f);
        sh_h1t[j * NB + v] = h;
    }
    __syncthreads();

    // Phase B: g2[v][j] = dinv[v] * sum_k h1t[k][v] * W2[k][j]
    int jt = t & 15;             // j-quad 0..15
    int vt = t >> 4;             // v-quad 0..15
    const float* hp = sh_h1t + vt * 4;
    const float* wp = W2 + jt * 4;
    float4 a0 = make_float4(0.f, 0.f, 0.f, 0.f), a1 = a0, a2 = a0, a3 = a0;
#pragma unroll 4
    for (int k = 0; k < HID; ++k) {
        float4 h4 = *(const float4*)(hp + k * NB);
        float4 w4 = *(const float4*)(wp + k * OUTC);
        a0.x += h4.x * w4.x; a0.y += h4.x * w4.y; a0.z += h4.x * w4.z; a0.w += h4.x * w4.w;
        a1.x += h4.y * w4.x; a1.y += h4.y * w4.y; a1.z += h4.y * w4.z; a1.w += h4.y * w4.w;
        a2.x += h4.z * w4.x; a2.y += h4.z * w4.y; a2.z += h4.z * w4.z; a2.w += h4.z * w4.w;
        a3.x += h4.w * w4.x; a3.y += h4.w * w4.y; a3.z += h4.w * w4.z; a3.w += h4.w * w4.w;
    }
    float4 accs[4] = {a0, a1, a2, a3};
#pragma unroll
    for (int a = 0; a < 4; ++a) {
        int vl = vt * 4 + a;
        int v = base + vl;
        if (v < n) {
            float dv = sh_dinv[vl];
            float4 o = make_float4(accs[a].x * dv, accs[a].y * dv,
                                   accs[a].z * dv, accs[a].w * dv);
            *(float4*)(g2 + (size_t)v * OUTC + jt * 4) = o;
        }
    }
}

// ---------------- layer 2 aggregation ----------------
// one wave per node: 4 neighbor slots x 16 feature-quads, shfl-down reduce
__global__ void __launch_bounds__(256)
k_agg2(const float* __restrict__ g2, const float* __restrict__ dinv,
       const int* __restrict__ rowptr, const int* __restrict__ cnt,
       const int* __restrict__ col, const float* __restrict__ b2,
       float* __restrict__ out, int n) {
    int t = threadIdx.x;
    int v = blockIdx.x * 4 + (t >> 6);   // wave-uniform
    if (v >= n) return;
    int lane = t & 63;
    int slot = lane >> 4, quad = lane & 15;
    int start = rowptr[v], len = cnt[v];
    float4 acc = make_float4(0.f, 0.f, 0.f, 0.f);
    for (int it = slot; it < len; it += 4) {
        int s = col[start + it];
        float4 g = *(const float4*)(g2 + (size_t)s * OUTC + quad * 4);
        acc.x += g.x; acc.y += g.y; acc.z += g.z; acc.w += g.w;
    }
    acc.x += __shfl_down(acc.x, 16, 64);
    acc.y += __shfl_down(acc.y, 16, 64);
    acc.z += __shfl_down(acc.z, 16, 64);
    acc.w += __shfl_down(acc.w, 16, 64);
    acc.x += __shfl_down(acc.x, 32, 64);
    acc.y += __shfl_down(acc.y, 32, 64);
    acc.z += __shfl_down(acc.z, 32, 64);
    acc.w += __shfl_down(acc.w, 32, 64);
    if (lane < 16) {
        float4 self = *(const float4*)(g2 + (size_t)v * OUTC + quad * 4);
        float4 bb = *(const float4*)(b2 + quad * 4);
        float dv = dinv[v];
        float4 o = make_float4(dv * (acc.x + self.x) + bb.x,
                               dv * (acc.y + self.y) + bb.y,
                               dv * (acc.z + self.z) + bb.z,
                               dv * (acc.w + self.w) + bb.w);
        *(float4*)(out + (size_t)v * OUTC + quad * 4) = o;
    }
}

// ---------------- launch ----------------

extern "C" void kernel_launch(void* const* d_in, const int* in_sizes, int n_in,
                              void* d_out, int out_size, void* d_ws, size_t ws_size,
                              hipStream_t stream) {
    const float* x  = (const float*)d_in[0];
    const int*   ei = (const int*)d_in[1];
    const float* W1 = (const float*)d_in[2];
    const float* b1 = (const float*)d_in[3];
    const float* W2 = (const float*)d_in[4];
    const float* b2 = (const float*)d_in[5];
    float*       out = (float*)d_out;

    const int n = in_sizes[0] / IN_C;   // 100000
    const int E = in_sizes[1] / 2;      // 1600000
    const int* src = ei;
    const int* dst = ei + E;

    char* ws = (char*)d_ws;
    size_t off = 0;
    int* cnt       = (int*)(ws + off); off += (size_t)n * 4;
    int* rowptr    = (int*)(ws + off); off += (size_t)n * 4;
    int* cursor    = (int*)(ws + off); off += (size_t)n * 4;
    int* blocksums = (int*)(ws + off); off += 1024 * 4;
    int* col       = (int*)(ws + off); off += (size_t)E * 4;
    float* dinv    = (float*)(ws + off); off += (size_t)n * 4;
    float* xs      = (float*)(ws + off); off += (size_t)n * 8 * 4;
    float* xagg8   = (float*)(ws + off); off += (size_t)n * 8 * 4;
    float* g2      = (float*)(ws + off); off += (size_t)n * OUTC * 4;

    const int B = 256;
    const int nb_scan = (n + 1023) / 1024;

    hipMemsetAsync(cnt, 0, (size_t)n * 4, stream);
    k_hist<<<(E + B - 1) / B, B, 0, stream>>>(dst, cnt, E);
    k_scan_block<<<nb_scan, 1024, 0, stream>>>(cnt, rowptr, blocksums, n);
    k_scan_sums<<<1, 64, 0, stream>>>(blocksums, nb_scan);
    k_scan_add<<<(n + B - 1) / B, B, 0, stream>>>(rowptr, blocksums, cursor, cnt, x, dinv, xs, n);
    k_fill<<<(E + B - 1) / B, B, 0, stream>>>(src, dst, cursor, col, E);

    k_agg1<<<(2 * n + B - 1) / B, B, 0, stream>>>(xs, rowptr, cnt, col, xagg8, n);
    k_fused<<<(n + NB - 1) / NB, B, 0, stream>>>(xagg8, dinv, W1, b1, W2, g2, n);
    k_agg2<<<(n + 3) / 4, B, 0, stream>>>(g2, dinv, rowptr, cnt, col, b2, out, n);
}

// Round 4
// 264.820 us; speedup vs baseline: 4.2623x; 1.5202x over previous
//
#include <hip/hip_runtime.h>

#define IN_C 5
#define HID  128
#define OUTC 64

#define NBUCK_MAX 256     // buckets = ceil(n/512); n=100000 -> 196
#define BCAP      12288   // per-bucket region capacity (mean 8192, sigma ~90)

// ---------------- CSR build: 2-pass LDS counting sort ----------------

// Pass A: bin edges by dst>>9. Per-block LDS histogram; one global atomic per
// (block,bucket) reserves a contiguous range; packed (src<<9)|dstlow written
// sequentially into it.
__global__ void __launch_bounds__(256)
k_bin(const int* __restrict__ src, const int* __restrict__ dst,
      int* __restrict__ bucket_cnt, unsigned* __restrict__ binned, int E) {
    __shared__ int hist[NBUCK_MAX], base[NBUCK_MAX], cur[NBUCK_MAX];
    int t = threadIdx.x;
    for (int i = t; i < NBUCK_MAX; i += 256) { hist[i] = 0; cur[i] = 0; }
    __syncthreads();
    int per = (E + gridDim.x - 1) / gridDim.x;
    int lo = blockIdx.x * per, hi = min(E, lo + per);
    for (int e = lo + t; e < hi; e += 256)
        atomicAdd(&hist[dst[e] >> 9], 1);
    __syncthreads();
    for (int i = t; i < NBUCK_MAX; i += 256)
        if (hist[i] > 0) base[i] = atomicAdd(&bucket_cnt[i], hist[i]);
    __syncthreads();
    for (int e = lo + t; e < hi; e += 256) {
        int d = dst[e];
        int b = d >> 9;
        unsigned p = ((unsigned)src[e] << 9) | (unsigned)(d & 511);
        int r = atomicAdd(&cur[b], 1);
        binned[(size_t)b * BCAP + base[b] + r] = p;
    }
}

// tiny exclusive scan of bucket totals (<=256 values)
__global__ void k_bucket_scan(const int* __restrict__ bucket_cnt,
                              int* __restrict__ bucket_base, int nb) {
    if (threadIdx.x == 0 && blockIdx.x == 0) {
        int acc = 0;
        for (int i = 0; i < nb; ++i) { bucket_base[i] = acc; acc += bucket_cnt[i]; }
    }
}

// Pass B: one block per bucket (512 nodes). LDS histogram of dst low bits ->
// cnt/rowptr/dinv/xs (coalesced), then scatter col into the bucket's
// contiguous region. No global atomics.
__global__ void __launch_bounds__(256)
k_csr(const unsigned* __restrict__ binned, const int* __restrict__ bucket_cnt,
      const int* __restrict__ bucket_base, const float* __restrict__ x,
      int* __restrict__ rowptr, int* __restrict__ cnt, float* __restrict__ dinv,
      float* __restrict__ xs, int* __restrict__ col, int n) {
    __shared__ int hist[512], rstart[512], cur[512];
    __shared__ int chunk_tot[8], chunk_off[8];
    int b = blockIdx.x;
    int t = threadIdx.x;
    int m = bucket_cnt[b];
    int ebase = bucket_base[b];
    const unsigned* bin = binned + (size_t)b * BCAP;

    for (int i = t; i < 512; i += 256) hist[i] = 0;
    __syncthreads();
    for (int e = t; e < m; e += 256)
        atomicAdd(&hist[bin[e] & 511], 1);
    __syncthreads();
    if (t < 8) {
        int acc = 0;
        for (int i = 0; i < 64; ++i) { int idx = t * 64 + i; rstart[idx] = acc; acc += hist[idx]; }
        chunk_tot[t] = acc;
    }
    __syncthreads();
    if (t == 0) {
        int acc = 0;
        for (int i = 0; i < 8; ++i) { chunk_off[i] = acc; acc += chunk_tot[i]; }
    }
    __syncthreads();
    for (int i = t; i < 512; i += 256) {
        int rs = rstart[i] + chunk_off[i >> 6];
        cur[i] = rs;
        int v = b * 512 + i;
        if (v < n) {
            rowptr[v] = ebase + rs;
            int c = hist[i];
            cnt[v] = c;
            float dv = rsqrtf(1.0f + (float)c);
            dinv[v] = dv;
            const float* xp = x + (size_t)v * IN_C;
            float4* o = (float4*)(xs + (size_t)v * 8);
            o[0] = make_float4(xp[0] * dv, xp[1] * dv, xp[2] * dv, xp[3] * dv);
            o[1] = make_float4(xp[4] * dv, 0.f, 0.f, 0.f);
        }
    }
    __syncthreads();
    for (int e = t; e < m; e += 256) {
        unsigned p = bin[e];
        int pos = atomicAdd(&cur[p & 511], 1);
        col[ebase + pos] = (int)(p >> 9);
    }
}

// ---------------- layer 1 aggregation (5-dim, padded to 8) ----------------
__global__ void k_agg1(const float* __restrict__ xs, const int* __restrict__ rowptr,
                       const int* __restrict__ cnt, const int* __restrict__ col,
                       float* __restrict__ xagg8, int n) {
    int i = blockIdx.x * blockDim.x + threadIdx.x;
    int v = i >> 1, half = (i & 1) * 4;
    if (v < n) {
        float4 acc = *(const float4*)(xs + (size_t)v * 8 + half);
        int start = rowptr[v], len = cnt[v];
        for (int k = 0; k < len; ++k) {
            int s = col[start + k];
            float4 t = *(const float4*)(xs + (size_t)s * 8 + half);
            acc.x += t.x; acc.y += t.y; acc.z += t.z; acc.w += t.w;
        }
        *(float4*)(xagg8 + (size_t)v * 8 + half) = acc;
    }
}

// ---------------- fused gemm1+relu+gemm2 ----------------
#define NB 64
__global__ void __launch_bounds__(256, 4)
k_fused(const float* __restrict__ xagg8, const float* __restrict__ dinv,
        const float* __restrict__ W1, const float* __restrict__ b1,
        const float* __restrict__ W2, float* __restrict__ g2, int n) {
    __shared__ float sh_h1t[HID * NB];     // 32 KB, [j][v]
    __shared__ float sh_xa[NB * 9];
    __shared__ float sh_dinv[NB];
    int t = threadIdx.x;
    int base = blockIdx.x * NB;

    if (t < NB) {
        int v = base + t;
        float4 a = make_float4(0.f, 0.f, 0.f, 0.f), b = a;
        float dv = 0.f;
        if (v < n) {
            const float4* p = (const float4*)(xagg8 + (size_t)v * 8);
            a = p[0]; b = p[1];
            dv = dinv[v];
        }
        float* sx = sh_xa + t * 9;
        sx[0] = a.x; sx[1] = a.y; sx[2] = a.z; sx[3] = a.w; sx[4] = b.x;
        sh_dinv[t] = dv;
    }
    __syncthreads();

    for (int p = 0; p < 32; ++p) {
        int idx = p * 256 + t;
        int v = idx & 63;
        int j = idx >> 6;
        const float* xa = sh_xa + v * 9;
        float acc = 0.f;
#pragma unroll
        for (int k = 0; k < IN_C; ++k)
            acc += xa[k] * W1[k * HID + j];
        sh_h1t[j * NB + v] = fmaxf(acc * sh_dinv[v] + b1[j], 0.f);
    }
    __syncthreads();

    int jt = t & 15;
    int vt = t >> 4;
    const float* hp = sh_h1t + vt * 4;
    const float* wp = W2 + jt * 4;
    float4 a0 = make_float4(0.f, 0.f, 0.f, 0.f), a1 = a0, a2 = a0, a3 = a0;
#pragma unroll 4
    for (int k = 0; k < HID; ++k) {
        float4 h4 = *(const float4*)(hp + k * NB);
        float4 w4 = *(const float4*)(wp + k * OUTC);
        a0.x += h4.x * w4.x; a0.y += h4.x * w4.y; a0.z += h4.x * w4.z; a0.w += h4.x * w4.w;
        a1.x += h4.y * w4.x; a1.y += h4.y * w4.y; a1.z += h4.y * w4.z; a1.w += h4.y * w4.w;
        a2.x += h4.z * w4.x; a2.y += h4.z * w4.y; a2.z += h4.z * w4.z; a2.w += h4.z * w4.w;
        a3.x += h4.w * w4.x; a3.y += h4.w * w4.y; a3.z += h4.w * w4.z; a3.w += h4.w * w4.w;
    }
    float4 accs[4] = {a0, a1, a2, a3};
#pragma unroll
    for (int a = 0; a < 4; ++a) {
        int vl = vt * 4 + a;
        int v = base + vl;
        if (v < n) {
            float dv = sh_dinv[vl];
            *(float4*)(g2 + (size_t)v * OUTC + jt * 4) =
                make_float4(accs[a].x * dv, accs[a].y * dv, accs[a].z * dv, accs[a].w * dv);
        }
    }
}

// ---------------- layer 2 aggregation ----------------
__global__ void __launch_bounds__(256)
k_agg2(const float* __restrict__ g2, const float* __restrict__ dinv,
       const int* __restrict__ rowptr, const int* __restrict__ cnt,
       const int* __restrict__ col, const float* __restrict__ b2,
       float* __restrict__ out, int n) {
    int t = threadIdx.x;
    int v = blockIdx.x * 4 + (t >> 6);
    if (v >= n) return;
    int lane = t & 63;
    int slot = lane >> 4, quad = lane & 15;
    int start = rowptr[v], len = cnt[v];
    float4 acc = make_float4(0.f, 0.f, 0.f, 0.f);
    for (int it = slot; it < len; it += 4) {
        int s = col[start + it];
        float4 g = *(const float4*)(g2 + (size_t)s * OUTC + quad * 4);
        acc.x += g.x; acc.y += g.y; acc.z += g.z; acc.w += g.w;
    }
    acc.x += __shfl_down(acc.x, 16, 64);
    acc.y += __shfl_down(acc.y, 16, 64);
    acc.z += __shfl_down(acc.z, 16, 64);
    acc.w += __shfl_down(acc.w, 16, 64);
    acc.x += __shfl_down(acc.x, 32, 64);
    acc.y += __shfl_down(acc.y, 32, 64);
    acc.z += __shfl_down(acc.z, 32, 64);
    acc.w += __shfl_down(acc.w, 32, 64);
    if (lane < 16) {
        float4 self = *(const float4*)(g2 + (size_t)v * OUTC + quad * 4);
        float4 bb = *(const float4*)(b2 + quad * 4);
        float dv = dinv[v];
        *(float4*)(out + (size_t)v * OUTC + quad * 4) =
            make_float4(dv * (acc.x + self.x) + bb.x,
                        dv * (acc.y + self.y) + bb.y,
                        dv * (acc.z + self.z) + bb.z,
                        dv * (acc.w + self.w) + bb.w);
    }
}

// ---------------- launch ----------------

extern "C" void kernel_launch(void* const* d_in, const int* in_sizes, int n_in,
                              void* d_out, int out_size, void* d_ws, size_t ws_size,
                              hipStream_t stream) {
    const float* x  = (const float*)d_in[0];
    const int*   ei = (const int*)d_in[1];
    const float* W1 = (const float*)d_in[2];
    const float* b1 = (const float*)d_in[3];
    const float* W2 = (const float*)d_in[4];
    const float* b2 = (const float*)d_in[5];
    float*       out = (float*)d_out;

    const int n = in_sizes[0] / IN_C;   // 100000
    const int E = in_sizes[1] / 2;      // 1600000
    const int* src = ei;
    const int* dst = ei + E;
    const int nbuck = (n + 511) / 512;  // 196

    char* ws = (char*)d_ws;
    size_t off = 0;
    int* cnt         = (int*)(ws + off); off += (size_t)n * 4;
    int* rowptr      = (int*)(ws + off); off += (size_t)n * 4;
    int* col         = (int*)(ws + off); off += (size_t)E * 4;
    float* dinv      = (float*)(ws + off); off += (size_t)n * 4;
    float* xs        = (float*)(ws + off); off += (size_t)n * 8 * 4;
    float* xagg8     = (float*)(ws + off); off += (size_t)n * 8 * 4;
    float* g2        = (float*)(ws + off); off += (size_t)n * OUTC * 4;
    int* bucket_cnt  = (int*)(ws + off); off += NBUCK_MAX * 4;
    int* bucket_base = (int*)(ws + off); off += NBUCK_MAX * 4;
    unsigned* binned = (unsigned*)(ws + off); off += (size_t)NBUCK_MAX * BCAP * 4;

    const int B = 256;

    hipMemsetAsync(bucket_cnt, 0, NBUCK_MAX * 4, stream);
    k_bin<<<256, B, 0, stream>>>(src, dst, bucket_cnt, binned, E);
    k_bucket_scan<<<1, 64, 0, stream>>>(bucket_cnt, bucket_base, nbuck);
    k_csr<<<nbuck, B, 0, stream>>>(binned, bucket_cnt, bucket_base, x,
                                   rowptr, cnt, dinv, xs, col, n);

    k_agg1<<<(2 * n + B - 1) / B, B, 0, stream>>>(xs, rowptr, cnt, col, xagg8, n);
    k_fused<<<(n + NB - 1) / NB, B, 0, stream>>>(xagg8, dinv, W1, b1, W2, g2, n);
    k_agg2<<<(n + 3) / 4, B, 0, stream>>>(g2, dinv, rowptr, cnt, col, b2, out, n);
}

// Round 5
// 255.036 us; speedup vs baseline: 4.4258x; 1.0384x over previous
//
#include <hip/hip_runtime.h>
#include <hip/hip_fp16.h>

#define IN_C 5
#define HID  128
#define OUTC 64

#define NBUCK_MAX 256     // buckets = ceil(n/512); n=100000 -> 196
#define BCAP      12288   // per-bucket region capacity (mean 8192, sigma ~90)

// ---------------- CSR build: 2-pass LDS counting sort ----------------

__global__ void __launch_bounds__(256)
k_bin(const int* __restrict__ src, const int* __restrict__ dst,
      int* __restrict__ bucket_cnt, unsigned* __restrict__ binned, int E) {
    __shared__ int hist[NBUCK_MAX], base[NBUCK_MAX], cur[NBUCK_MAX];
    int t = threadIdx.x;
    for (int i = t; i < NBUCK_MAX; i += 256) { hist[i] = 0; cur[i] = 0; }
    __syncthreads();
    int per = (E + gridDim.x - 1) / gridDim.x;
    int lo = blockIdx.x * per, hi = min(E, lo + per);
    for (int e = lo + t; e < hi; e += 256)
        atomicAdd(&hist[dst[e] >> 9], 1);
    __syncthreads();
    for (int i = t; i < NBUCK_MAX; i += 256)
        if (hist[i] > 0) base[i] = atomicAdd(&bucket_cnt[i], hist[i]);
    __syncthreads();
    for (int e = lo + t; e < hi; e += 256) {
        int d = dst[e];
        int b = d >> 9;
        unsigned p = ((unsigned)src[e] << 9) | (unsigned)(d & 511);
        int r = atomicAdd(&cur[b], 1);
        binned[(size_t)b * BCAP + base[b] + r] = p;
    }
}

__global__ void k_bucket_scan(const int* __restrict__ bucket_cnt,
                              int* __restrict__ bucket_base, int nb) {
    if (threadIdx.x == 0 && blockIdx.x == 0) {
        int acc = 0;
        for (int i = 0; i < nb; ++i) { bucket_base[i] = acc; acc += bucket_cnt[i]; }
    }
}

// Pass B: one block per bucket (512 nodes). Also emits xs as fp16[8] per node.
__global__ void __launch_bounds__(256)
k_csr(const unsigned* __restrict__ binned, const int* __restrict__ bucket_cnt,
      const int* __restrict__ bucket_base, const float* __restrict__ x,
      int* __restrict__ rowptr, int* __restrict__ cnt, float* __restrict__ dinv,
      __half* __restrict__ xs, int* __restrict__ col, int n) {
    __shared__ int hist[512], rstart[512], cur[512];
    __shared__ int chunk_tot[8], chunk_off[8];
    int b = blockIdx.x;
    int t = threadIdx.x;
    int m = bucket_cnt[b];
    int ebase = bucket_base[b];
    const unsigned* bin = binned + (size_t)b * BCAP;

    for (int i = t; i < 512; i += 256) hist[i] = 0;
    __syncthreads();
    for (int e = t; e < m; e += 256)
        atomicAdd(&hist[bin[e] & 511], 1);
    __syncthreads();
    if (t < 8) {
        int acc = 0;
        for (int i = 0; i < 64; ++i) { int idx = t * 64 + i; rstart[idx] = acc; acc += hist[idx]; }
        chunk_tot[t] = acc;
    }
    __syncthreads();
    if (t == 0) {
        int acc = 0;
        for (int i = 0; i < 8; ++i) { chunk_off[i] = acc; acc += chunk_tot[i]; }
    }
    __syncthreads();
    for (int i = t; i < 512; i += 256) {
        int rs = rstart[i] + chunk_off[i >> 6];
        cur[i] = rs;
        int v = b * 512 + i;
        if (v < n) {
            rowptr[v] = ebase + rs;
            int c = hist[i];
            cnt[v] = c;
            float dv = rsqrtf(1.0f + (float)c);
            dinv[v] = dv;
            const float* xp = x + (size_t)v * IN_C;
            __half2 h[4];
            h[0] = __floats2half2_rn(xp[0] * dv, xp[1] * dv);
            h[1] = __floats2half2_rn(xp[2] * dv, xp[3] * dv);
            h[2] = __floats2half2_rn(xp[4] * dv, 0.f);
            h[3] = __floats2half2_rn(0.f, 0.f);
            *(uint4*)(xs + (size_t)v * 8) = *(uint4*)h;
        }
    }
    __syncthreads();
    for (int e = t; e < m; e += 256) {
        unsigned p = bin[e];
        int pos = atomicAdd(&cur[p & 511], 1);
        col[ebase + pos] = (int)(p >> 9);
    }
}

// ---------------- layer 1 aggregation: 1 thread/node, fp16 gather ----------------
__global__ void __launch_bounds__(256)
k_agg1(const __half* __restrict__ xs, const int* __restrict__ rowptr,
       const int* __restrict__ cnt, const int* __restrict__ col,
       float* __restrict__ xagg8, int n) {
    int v = blockIdx.x * blockDim.x + threadIdx.x;
    if (v >= n) return;
    uint4 raw = *(const uint4*)(xs + (size_t)v * 8);
    const __half2* h = (const __half2*)&raw;
    float2 f0 = __half22float2(h[0]), f1 = __half22float2(h[1]), f2 = __half22float2(h[2]);
    float a0 = f0.x, a1 = f0.y, a2 = f1.x, a3 = f1.y, a4 = f2.x;
    int start = rowptr[v], len = cnt[v];
    for (int k = 0; k < len; ++k) {
        int s = col[start + k];
        uint4 r = *(const uint4*)(xs + (size_t)s * 8);
        const __half2* g = (const __half2*)&r;
        float2 g0 = __half22float2(g[0]), g1 = __half22float2(g[1]), g2v = __half22float2(g[2]);
        a0 += g0.x; a1 += g0.y; a2 += g1.x; a3 += g1.y; a4 += g2v.x;
    }
    float4* o = (float4*)(xagg8 + (size_t)v * 8);
    o[0] = make_float4(a0, a1, a2, a3);
    o[1] = make_float4(a4, 0.f, 0.f, 0.f);
}

// ---------------- fused gemm1+relu+gemm2, fp16 g2 output ----------------
#define NB 64
__global__ void __launch_bounds__(256, 4)
k_fused(const float* __restrict__ xagg8, const float* __restrict__ dinv,
        const float* __restrict__ W1, const float* __restrict__ b1,
        const float* __restrict__ W2, __half* __restrict__ g2, int n) {
    __shared__ float sh_h1t[HID * NB];     // 32 KB, [j][v]
    __shared__ float sh_xa[NB * 9];
    __shared__ float sh_dinv[NB];
    int t = threadIdx.x;
    int base = blockIdx.x * NB;

    if (t < NB) {
        int v = base + t;
        float4 a = make_float4(0.f, 0.f, 0.f, 0.f), b = a;
        float dv = 0.f;
        if (v < n) {
            const float4* p = (const float4*)(xagg8 + (size_t)v * 8);
            a = p[0]; b = p[1];
            dv = dinv[v];
        }
        float* sx = sh_xa + t * 9;
        sx[0] = a.x; sx[1] = a.y; sx[2] = a.z; sx[3] = a.w; sx[4] = b.x;
        sh_dinv[t] = dv;
    }
    __syncthreads();

    for (int p = 0; p < 32; ++p) {
        int idx = p * 256 + t;
        int v = idx & 63;
        int j = idx >> 6;
        const float* xa = sh_xa + v * 9;
        float acc = 0.f;
#pragma unroll
        for (int k = 0; k < IN_C; ++k)
            acc += xa[k] * W1[k * HID + j];
        sh_h1t[j * NB + v] = fmaxf(acc * sh_dinv[v] + b1[j], 0.f);
    }
    __syncthreads();

    int jt = t & 15;
    int vt = t >> 4;
    const float* hp = sh_h1t + vt * 4;
    const float* wp = W2 + jt * 4;
    float4 a0 = make_float4(0.f, 0.f, 0.f, 0.f), a1 = a0, a2 = a0, a3 = a0;
#pragma unroll 4
    for (int k = 0; k < HID; ++k) {
        float4 h4 = *(const float4*)(hp + k * NB);
        float4 w4 = *(const float4*)(wp + k * OUTC);
        a0.x += h4.x * w4.x; a0.y += h4.x * w4.y; a0.z += h4.x * w4.z; a0.w += h4.x * w4.w;
        a1.x += h4.y * w4.x; a1.y += h4.y * w4.y; a1.z += h4.y * w4.z; a1.w += h4.y * w4.w;
        a2.x += h4.z * w4.x; a2.y += h4.z * w4.y; a2.z += h4.z * w4.z; a2.w += h4.z * w4.w;
        a3.x += h4.w * w4.x; a3.y += h4.w * w4.y; a3.z += h4.w * w4.z; a3.w += h4.w * w4.w;
    }
    float4 accs[4] = {a0, a1, a2, a3};
#pragma unroll
    for (int a = 0; a < 4; ++a) {
        int vl = vt * 4 + a;
        int v = base + vl;
        if (v < n) {
            float dv = sh_dinv[vl];
            __half2 h[2];
            h[0] = __floats2half2_rn(accs[a].x * dv, accs[a].y * dv);
            h[1] = __floats2half2_rn(accs[a].z * dv, accs[a].w * dv);
            *(uint2*)(g2 + (size_t)v * OUTC + jt * 4) = *(uint2*)h;
        }
    }
}

// ---------------- layer 2 aggregation: fp16 gather ----------------
__global__ void __launch_bounds__(256)
k_agg2(const __half* __restrict__ g2, const float* __restrict__ dinv,
       const int* __restrict__ rowptr, const int* __restrict__ cnt,
       const int* __restrict__ col, const float* __restrict__ b2,
       float* __restrict__ out, int n) {
    int t = threadIdx.x;
    int v = blockIdx.x * 4 + (t >> 6);
    if (v >= n) return;
    int lane = t & 63;
    int slot = lane >> 4, quad = lane & 15;
    int start = rowptr[v], len = cnt[v];
    float4 acc = make_float4(0.f, 0.f, 0.f, 0.f);
    for (int it = slot; it < len; it += 4) {
        int s = col[start + it];
        uint2 raw = *(const uint2*)(g2 + (size_t)s * OUTC + quad * 4);
        const __half2* h = (const __half2*)&raw;
        float2 f0 = __half22float2(h[0]), f1 = __half22float2(h[1]);
        acc.x += f0.x; acc.y += f0.y; acc.z += f1.x; acc.w += f1.y;
    }
    acc.x += __shfl_down(acc.x, 16, 64);
    acc.y += __shfl_down(acc.y, 16, 64);
    acc.z += __shfl_down(acc.z, 16, 64);
    acc.w += __shfl_down(acc.w, 16, 64);
    acc.x += __shfl_down(acc.x, 32, 64);
    acc.y += __shfl_down(acc.y, 32, 64);
    acc.z += __shfl_down(acc.z, 32, 64);
    acc.w += __shfl_down(acc.w, 32, 64);
    if (lane < 16) {
        uint2 raw = *(const uint2*)(g2 + (size_t)v * OUTC + quad * 4);
        const __half2* h = (const __half2*)&raw;
        float2 s0 = __half22float2(h[0]), s1 = __half22float2(h[1]);
        float4 bb = *(const float4*)(b2 + quad * 4);
        float dv = dinv[v];
        *(float4*)(out + (size_t)v * OUTC + quad * 4) =
            make_float4(dv * (acc.x + s0.x) + bb.x,
                        dv * (acc.y + s0.y) + bb.y,
                        dv * (acc.z + s1.x) + bb.z,
                        dv * (acc.w + s1.y) + bb.w);
    }
}

// ---------------- launch ----------------

extern "C" void kernel_launch(void* const* d_in, const int* in_sizes, int n_in,
                              void* d_out, int out_size, void* d_ws, size_t ws_size,
                              hipStream_t stream) {
    const float* x  = (const float*)d_in[0];
    const int*   ei = (const int*)d_in[1];
    const float* W1 = (const float*)d_in[2];
    const float* b1 = (const float*)d_in[3];
    const float* W2 = (const float*)d_in[4];
    const float* b2 = (const float*)d_in[5];
    float*       out = (float*)d_out;

    const int n = in_sizes[0] / IN_C;   // 100000
    const int E = in_sizes[1] / 2;      // 1600000
    const int* src = ei;
    const int* dst = ei + E;
    const int nbuck = (n + 511) / 512;  // 196

    char* ws = (char*)d_ws;
    size_t off = 0;
    int* cnt         = (int*)(ws + off); off += (size_t)n * 4;
    int* rowptr      = (int*)(ws + off); off += (size_t)n * 4;
    int* col         = (int*)(ws + off); off += (size_t)E * 4;
    float* dinv      = (float*)(ws + off); off += (size_t)n * 4;
    __half* xs       = (__half*)(ws + off); off += (size_t)n * 8 * 2;
    float* xagg8     = (float*)(ws + off); off += (size_t)n * 8 * 4;
    __half* g2       = (__half*)(ws + off); off += (size_t)n * OUTC * 2;
    int* bucket_cnt  = (int*)(ws + off); off += NBUCK_MAX * 4;
    int* bucket_base = (int*)(ws + off); off += NBUCK_MAX * 4;
    unsigned* binned = (unsigned*)(ws + off); off += (size_t)NBUCK_MAX * BCAP * 4;

    const int B = 256;

    hipMemsetAsync(bucket_cnt, 0, NBUCK_MAX * 4, stream);
    k_bin<<<256, B, 0, stream>>>(src, dst, bucket_cnt, binned, E);
    k_bucket_scan<<<1, 64, 0, stream>>>(bucket_cnt, bucket_base, nbuck);
    k_csr<<<nbuck, B, 0, stream>>>(binned, bucket_cnt, bucket_base, x,
                                   rowptr, cnt, dinv, xs, col, n);

    k_agg1<<<(n + B - 1) / B, B, 0, stream>>>(xs, rowptr, cnt, col, xagg8, n);
    k_fused<<<(n + NB - 1) / NB, B, 0, stream>>>(xagg8, dinv, W1, b1, W2, g2, n);
    k_agg2<<<(n + 3) / 4, B, 0, stream>>>(g2, dinv, rowptr, cnt, col, b2, out, n);
}

// Round 6
// 233.210 us; speedup vs baseline: 4.8400x; 1.0936x over previous
//
#include <hip/hip_runtime.h>
#include <hip/hip_fp16.h>

#define IN_C 5
#define HID  128
#define OUTC 64

#define NBUCK_MAX 256     // buckets = ceil(n/512); n=100000 -> 196
#define BCAP      12288   // per-bucket region capacity (mean 8192, sigma ~90)

// ---------------- CSR build: 2-pass LDS counting sort ----------------

__global__ void __launch_bounds__(256)
k_bin(const int* __restrict__ src, const int* __restrict__ dst,
      int* __restrict__ bucket_cnt, unsigned* __restrict__ binned, int E) {
    __shared__ int hist[NBUCK_MAX], base[NBUCK_MAX], cur[NBUCK_MAX];
    int t = threadIdx.x;
    for (int i = t; i < NBUCK_MAX; i += 256) { hist[i] = 0; cur[i] = 0; }
    __syncthreads();
    int per = (E + gridDim.x - 1) / gridDim.x;
    int lo = blockIdx.x * per, hi = min(E, lo + per);
    for (int e = lo + t; e < hi; e += 256)
        atomicAdd(&hist[dst[e] >> 9], 1);
    __syncthreads();
    for (int i = t; i < NBUCK_MAX; i += 256)
        if (hist[i] > 0) base[i] = atomicAdd(&bucket_cnt[i], hist[i]);
    __syncthreads();
    for (int e = lo + t; e < hi; e += 256) {
        int d = dst[e];
        int b = d >> 9;
        unsigned p = ((unsigned)src[e] << 9) | (unsigned)(d & 511);
        int r = atomicAdd(&cur[b], 1);
        binned[(size_t)b * BCAP + base[b] + r] = p;
    }
}

__global__ void k_bucket_scan(const int* __restrict__ bucket_cnt,
                              int* __restrict__ bucket_base, int nb) {
    if (threadIdx.x == 0 && blockIdx.x == 0) {
        int acc = 0;
        for (int i = 0; i < nb; ++i) { bucket_base[i] = acc; acc += bucket_cnt[i]; }
    }
}

// Pass B: one block per bucket (512 nodes). Also emits xs as fp16[8] per node.
__global__ void __launch_bounds__(256)
k_csr(const unsigned* __restrict__ binned, const int* __restrict__ bucket_cnt,
      const int* __restrict__ bucket_base, const float* __restrict__ x,
      int* __restrict__ rowptr, int* __restrict__ cnt, float* __restrict__ dinv,
      __half* __restrict__ xs, int* __restrict__ col, int n) {
    __shared__ int hist[512], rstart[512], cur[512];
    __shared__ int chunk_tot[8], chunk_off[8];
    int b = blockIdx.x;
    int t = threadIdx.x;
    int m = bucket_cnt[b];
    int ebase = bucket_base[b];
    const unsigned* bin = binned + (size_t)b * BCAP;

    for (int i = t; i < 512; i += 256) hist[i] = 0;
    __syncthreads();
    for (int e = t; e < m; e += 256)
        atomicAdd(&hist[bin[e] & 511], 1);
    __syncthreads();
    if (t < 8) {
        int acc = 0;
        for (int i = 0; i < 64; ++i) { int idx = t * 64 + i; rstart[idx] = acc; acc += hist[idx]; }
        chunk_tot[t] = acc;
    }
    __syncthreads();
    if (t == 0) {
        int acc = 0;
        for (int i = 0; i < 8; ++i) { chunk_off[i] = acc; acc += chunk_tot[i]; }
    }
    __syncthreads();
    for (int i = t; i < 512; i += 256) {
        int rs = rstart[i] + chunk_off[i >> 6];
        cur[i] = rs;
        int v = b * 512 + i;
        if (v < n) {
            rowptr[v] = ebase + rs;
            int c = hist[i];
            cnt[v] = c;
            float dv = rsqrtf(1.0f + (float)c);
            dinv[v] = dv;
            const float* xp = x + (size_t)v * IN_C;
            __half2 h[4];
            h[0] = __floats2half2_rn(xp[0] * dv, xp[1] * dv);
            h[1] = __floats2half2_rn(xp[2] * dv, xp[3] * dv);
            h[2] = __floats2half2_rn(xp[4] * dv, 0.f);
            h[3] = __floats2half2_rn(0.f, 0.f);
            *(uint4*)(xs + (size_t)v * 8) = *(uint4*)h;
        }
    }
    __syncthreads();
    for (int e = t; e < m; e += 256) {
        unsigned p = bin[e];
        int pos = atomicAdd(&cur[p & 511], 1);
        col[ebase + pos] = (int)(p >> 9);
    }
}

// ------- fused: layer-1 gather (4 threads/node) + gemm1+relu + gemm2, fp16 g2 -------
#define NB 64
__global__ void __launch_bounds__(256, 4)
k_fused(const __half* __restrict__ xs, const float* __restrict__ dinv,
        const int* __restrict__ rowptr, const int* __restrict__ cnt,
        const int* __restrict__ col,
        const float* __restrict__ W1, const float* __restrict__ b1,
        const float* __restrict__ W2, __half* __restrict__ g2, int n) {
    __shared__ float sh_h1t[HID * NB];     // 32 KB, [j][v]
    __shared__ float sh_xa[NB * 9];
    __shared__ float sh_dinv[NB];
    __shared__ int sh_start[NB], sh_len[NB];
    int t = threadIdx.x;
    int base = blockIdx.x * NB;

    if (t < NB) {
        int v = base + t;
        if (v < n) {
            sh_start[t] = rowptr[v];
            sh_len[t]   = cnt[v];
            sh_dinv[t]  = dinv[v];
        } else {
            sh_start[t] = 0; sh_len[t] = 0; sh_dinv[t] = 0.f;
        }
    }
    __syncthreads();

    // Gather phase: 4 threads per node, shfl-reduce over the 4-lane group
    {
        int vl = t >> 2, q = t & 3;
        int v = base + vl;
        int start = sh_start[vl], len = sh_len[vl];
        float a0 = 0.f, a1 = 0.f, a2 = 0.f, a3 = 0.f, a4 = 0.f;
        if (q == 0 && v < n) {
            uint4 r = *(const uint4*)(xs + (size_t)v * 8);
            const __half2* h = (const __half2*)&r;
            float2 f0 = __half22float2(h[0]), f1 = __half22float2(h[1]), f2 = __half22float2(h[2]);
            a0 = f0.x; a1 = f0.y; a2 = f1.x; a3 = f1.y; a4 = f2.x;
        }
        for (int k = q; k < len; k += 4) {
            int s = col[start + k];
            uint4 r = *(const uint4*)(xs + (size_t)s * 8);
            const __half2* h = (const __half2*)&r;
            float2 f0 = __half22float2(h[0]), f1 = __half22float2(h[1]), f2 = __half22float2(h[2]);
            a0 += f0.x; a1 += f0.y; a2 += f1.x; a3 += f1.y; a4 += f2.x;
        }
        a0 += __shfl_down(a0, 1, 64); a0 += __shfl_down(a0, 2, 64);
        a1 += __shfl_down(a1, 1, 64); a1 += __shfl_down(a1, 2, 64);
        a2 += __shfl_down(a2, 1, 64); a2 += __shfl_down(a2, 2, 64);
        a3 += __shfl_down(a3, 1, 64); a3 += __shfl_down(a3, 2, 64);
        a4 += __shfl_down(a4, 1, 64); a4 += __shfl_down(a4, 2, 64);
        if (q == 0) {
            float* sx = sh_xa + vl * 9;
            sx[0] = a0; sx[1] = a1; sx[2] = a2; sx[3] = a3; sx[4] = a4;
        }
    }
    __syncthreads();

    // Phase A: h1t[j][v] = relu(dinv[v]*dot(xa[v],W1[:,j]) + b1[j])
    for (int p = 0; p < 32; ++p) {
        int idx = p * 256 + t;
        int v = idx & 63;
        int j = idx >> 6;
        const float* xa = sh_xa + v * 9;
        float acc = 0.f;
#pragma unroll
        for (int k = 0; k < IN_C; ++k)
            acc += xa[k] * W1[k * HID + j];
        sh_h1t[j * NB + v] = fmaxf(acc * sh_dinv[v] + b1[j], 0.f);
    }
    __syncthreads();

    // Phase B: g2[v][j] = dinv[v] * sum_k h1t[k][v] * W2[k][j]
    int jt = t & 15;
    int vt = t >> 4;
    const float* hp = sh_h1t + vt * 4;
    const float* wp = W2 + jt * 4;
    float4 a0 = make_float4(0.f, 0.f, 0.f, 0.f), a1 = a0, a2 = a0, a3 = a0;
#pragma unroll 4
    for (int k = 0; k < HID; ++k) {
        float4 h4 = *(const float4*)(hp + k * NB);
        float4 w4 = *(const float4*)(wp + k * OUTC);
        a0.x += h4.x * w4.x; a0.y += h4.x * w4.y; a0.z += h4.x * w4.z; a0.w += h4.x * w4.w;
        a1.x += h4.y * w4.x; a1.y += h4.y * w4.y; a1.z += h4.y * w4.z; a1.w += h4.y * w4.w;
        a2.x += h4.z * w4.x; a2.y += h4.z * w4.y; a2.z += h4.z * w4.z; a2.w += h4.z * w4.w;
        a3.x += h4.w * w4.x; a3.y += h4.w * w4.y; a3.z += h4.w * w4.z; a3.w += h4.w * w4.w;
    }
    float4 accs[4] = {a0, a1, a2, a3};
#pragma unroll
    for (int a = 0; a < 4; ++a) {
        int vl = vt * 4 + a;
        int v = base + vl;
        if (v < n) {
            float dv = sh_dinv[vl];
            __half2 h[2];
            h[0] = __floats2half2_rn(accs[a].x * dv, accs[a].y * dv);
            h[1] = __floats2half2_rn(accs[a].z * dv, accs[a].w * dv);
            *(uint2*)(g2 + (size_t)v * OUTC + jt * 4) = *(uint2*)h;
        }
    }
}

// ---------------- layer 2 aggregation: 8 rows in flight per wave ----------------
__global__ void __launch_bounds__(256)
k_agg2(const __half* __restrict__ g2, const float* __restrict__ dinv,
       const int* __restrict__ rowptr, const int* __restrict__ cnt,
       const int* __restrict__ col, const float* __restrict__ b2,
       float* __restrict__ out, int n) {
    int t = threadIdx.x;
    int v = blockIdx.x * 4 + (t >> 6);   // wave-uniform
    if (v >= n) return;
    int lane = t & 63;
    int slot = lane >> 3;    // 0..7 neighbor slot
    int oct  = lane & 7;     // 0..7 feature octet (8 halves = 16B)
    int start = rowptr[v], len = cnt[v];
    float a0 = 0.f, a1 = 0.f, a2 = 0.f, a3 = 0.f, a4 = 0.f, a5 = 0.f, a6 = 0.f, a7 = 0.f;
    for (int it = slot; it < len; it += 8) {
        int s = col[start + it];
        uint4 raw = *(const uint4*)(g2 + (size_t)s * OUTC + oct * 8);
        const __half2* h = (const __half2*)&raw;
        float2 f0 = __half22float2(h[0]), f1 = __half22float2(h[1]);
        float2 f2 = __half22float2(h[2]), f3 = __half22float2(h[3]);
        a0 += f0.x; a1 += f0.y; a2 += f1.x; a3 += f1.y;
        a4 += f2.x; a5 += f2.y; a6 += f3.x; a7 += f3.y;
    }
#pragma unroll
    for (int d = 8; d <= 32; d <<= 1) {
        a0 += __shfl_down(a0, d, 64); a1 += __shfl_down(a1, d, 64);
        a2 += __shfl_down(a2, d, 64); a3 += __shfl_down(a3, d, 64);
        a4 += __shfl_down(a4, d, 64); a5 += __shfl_down(a5, d, 64);
        a6 += __shfl_down(a6, d, 64); a7 += __shfl_down(a7, d, 64);
    }
    if (lane < 8) {
        uint4 raw = *(const uint4*)(g2 + (size_t)v * OUTC + oct * 8);
        const __half2* h = (const __half2*)&raw;
        float2 s0 = __half22float2(h[0]), s1 = __half22float2(h[1]);
        float2 s2 = __half22float2(h[2]), s3 = __half22float2(h[3]);
        const float4* bp = (const float4*)(b2 + oct * 8);
        float4 bb0 = bp[0], bb1 = bp[1];
        float dv = dinv[v];
        float4 o0 = make_float4(dv * (a0 + s0.x) + bb0.x,
                                dv * (a1 + s0.y) + bb0.y,
                                dv * (a2 + s1.x) + bb0.z,
                                dv * (a3 + s1.y) + bb0.w);
        float4 o1 = make_float4(dv * (a4 + s2.x) + bb1.x,
                                dv * (a5 + s2.y) + bb1.y,
                                dv * (a6 + s3.x) + bb1.z,
                                dv * (a7 + s3.y) + bb1.w);
        float4* op = (float4*)(out + (size_t)v * OUTC + oct * 8);
        op[0] = o0; op[1] = o1;
    }
}

// ---------------- launch ----------------

extern "C" void kernel_launch(void* const* d_in, const int* in_sizes, int n_in,
                              void* d_out, int out_size, void* d_ws, size_t ws_size,
                              hipStream_t stream) {
    const float* x  = (const float*)d_in[0];
    const int*   ei = (const int*)d_in[1];
    const float* W1 = (const float*)d_in[2];
    const float* b1 = (const float*)d_in[3];
    const float* W2 = (const float*)d_in[4];
    const float* b2 = (const float*)d_in[5];
    float*       out = (float*)d_out;

    const int n = in_sizes[0] / IN_C;   // 100000
    const int E = in_sizes[1] / 2;      // 1600000
    const int* src = ei;
    const int* dst = ei + E;
    const int nbuck = (n + 511) / 512;  // 196

    char* ws = (char*)d_ws;
    size_t off = 0;
    int* cnt         = (int*)(ws + off); off += (size_t)n * 4;
    int* rowptr      = (int*)(ws + off); off += (size_t)n * 4;
    int* col         = (int*)(ws + off); off += (size_t)E * 4;
    float* dinv      = (float*)(ws + off); off += (size_t)n * 4;
    __half* xs       = (__half*)(ws + off); off += (size_t)n * 8 * 2;
    __half* g2       = (__half*)(ws + off); off += (size_t)n * OUTC * 2;
    int* bucket_cnt  = (int*)(ws + off); off += NBUCK_MAX * 4;
    int* bucket_base = (int*)(ws + off); off += NBUCK_MAX * 4;
    unsigned* binned = (unsigned*)(ws + off); off += (size_t)NBUCK_MAX * BCAP * 4;

    const int B = 256;

    hipMemsetAsync(bucket_cnt, 0, NBUCK_MAX * 4, stream);
    k_bin<<<256, B, 0, stream>>>(src, dst, bucket_cnt, binned, E);
    k_bucket_scan<<<1, 64, 0, stream>>>(bucket_cnt, bucket_base, nbuck);
    k_csr<<<nbuck, B, 0, stream>>>(binned, bucket_cnt, bucket_base, x,
                                   rowptr, cnt, dinv, xs, col, n);

    k_fused<<<(n + NB - 1) / NB, B, 0, stream>>>(xs, dinv, rowptr, cnt, col,
                                                 W1, b1, W2, g2, n);
    k_agg2<<<(n + 3) / 4, B, 0, stream>>>(g2, dinv, rowptr, cnt, col, b2, out, n);
}

// Round 7
// 226.048 us; speedup vs baseline: 4.9933x; 1.0317x over previous
//
#include <hip/hip_runtime.h>
#include <hip/hip_fp16.h>

#define IN_C 5
#define HID  128
#define OUTC 64

#define NBUCK_MAX 256     // buckets = ceil(n/512); n=100000 -> 196
#define BCAP      12288   // per-bucket region capacity (mean 8192, sigma ~90)

// ---------------- CSR build: 2-pass LDS counting sort ----------------

__global__ void __launch_bounds__(256)
k_bin(const int* __restrict__ src, const int* __restrict__ dst,
      int* __restrict__ bucket_cnt, unsigned* __restrict__ binned, int E) {
    __shared__ int hist[NBUCK_MAX], base[NBUCK_MAX], cur[NBUCK_MAX];
    int t = threadIdx.x;
    for (int i = t; i < NBUCK_MAX; i += 256) { hist[i] = 0; cur[i] = 0; }
    __syncthreads();
    int per = (E + gridDim.x - 1) / gridDim.x;
    int lo = blockIdx.x * per, hi = min(E, lo + per);
    for (int e = lo + t; e < hi; e += 256)
        atomicAdd(&hist[dst[e] >> 9], 1);
    __syncthreads();
    for (int i = t; i < NBUCK_MAX; i += 256)
        if (hist[i] > 0) base[i] = atomicAdd(&bucket_cnt[i], hist[i]);
    __syncthreads();
    for (int e = lo + t; e < hi; e += 256) {
        int d = dst[e];
        int b = d >> 9;
        unsigned p = ((unsigned)src[e] << 9) | (unsigned)(d & 511);
        int r = atomicAdd(&cur[b], 1);
        binned[(size_t)b * BCAP + base[b] + r] = p;
    }
}

__global__ void k_bucket_scan(const int* __restrict__ bucket_cnt,
                              int* __restrict__ bucket_base, int nb) {
    if (threadIdx.x == 0 && blockIdx.x == 0) {
        int acc = 0;
        for (int i = 0; i < nb; ++i) { bucket_base[i] = acc; acc += bucket_cnt[i]; }
    }
}

// Pass B: one block per bucket (512 nodes). Also emits xs as fp16[8] per node.
__global__ void __launch_bounds__(256)
k_csr(const unsigned* __restrict__ binned, const int* __restrict__ bucket_cnt,
      const int* __restrict__ bucket_base, const float* __restrict__ x,
      int* __restrict__ rowptr, int* __restrict__ cnt, float* __restrict__ dinv,
      __half* __restrict__ xs, int* __restrict__ col, int n) {
    __shared__ int hist[512], rstart[512], cur[512];
    __shared__ int chunk_tot[8], chunk_off[8];
    int b = blockIdx.x;
    int t = threadIdx.x;
    int m = bucket_cnt[b];
    int ebase = bucket_base[b];
    const unsigned* bin = binned + (size_t)b * BCAP;

    for (int i = t; i < 512; i += 256) hist[i] = 0;
    __syncthreads();
    for (int e = t; e < m; e += 256)
        atomicAdd(&hist[bin[e] & 511], 1);
    __syncthreads();
    if (t < 8) {
        int acc = 0;
        for (int i = 0; i < 64; ++i) { int idx = t * 64 + i; rstart[idx] = acc; acc += hist[idx]; }
        chunk_tot[t] = acc;
    }
    __syncthreads();
    if (t == 0) {
        int acc = 0;
        for (int i = 0; i < 8; ++i) { chunk_off[i] = acc; acc += chunk_tot[i]; }
    }
    __syncthreads();
    for (int i = t; i < 512; i += 256) {
        int rs = rstart[i] + chunk_off[i >> 6];
        cur[i] = rs;
        int v = b * 512 + i;
        if (v < n) {
            rowptr[v] = ebase + rs;
            int c = hist[i];
            cnt[v] = c;
            float dv = rsqrtf(1.0f + (float)c);
            dinv[v] = dv;
            const float* xp = x + (size_t)v * IN_C;
            __half2 h[4];
            h[0] = __floats2half2_rn(xp[0] * dv, xp[1] * dv);
            h[1] = __floats2half2_rn(xp[2] * dv, xp[3] * dv);
            h[2] = __floats2half2_rn(xp[4] * dv, 0.f);
            h[3] = __floats2half2_rn(0.f, 0.f);
            *(uint4*)(xs + (size_t)v * 8) = *(uint4*)h;
        }
    }
    __syncthreads();
    for (int e = t; e < m; e += 256) {
        unsigned p = bin[e];
        int pos = atomicAdd(&cur[p & 511], 1);
        col[ebase + pos] = (int)(p >> 9);
    }
}

// ------- fused: layer-1 gather (8 thr/node) + gemm1+relu + gemm2 (fp16 h1) -------
#define NB 64
__global__ void __launch_bounds__(256, 8)
k_fused(const __half* __restrict__ xs, const float* __restrict__ dinv,
        const int* __restrict__ rowptr, const int* __restrict__ cnt,
        const int* __restrict__ col,
        const float* __restrict__ W1, const float* __restrict__ b1,
        const float* __restrict__ W2, __half* __restrict__ g2, int n) {
    __shared__ __half sh_h1[HID * NB];     // 16 KB, [j][v] fp16
    __shared__ float sh_xa[NB * 9];
    __shared__ float sh_dinv[NB];
    __shared__ int sh_start[NB], sh_len[NB];
    int t = threadIdx.x;
    int base = blockIdx.x * NB;

    if (t < NB) {
        int v = base + t;
        if (v < n) {
            sh_start[t] = rowptr[v];
            sh_len[t]   = cnt[v];
            sh_dinv[t]  = dinv[v];
        } else {
            sh_start[t] = 0; sh_len[t] = 0; sh_dinv[t] = 0.f;
        }
    }
    __syncthreads();

    // Gather: 8 threads per node, 2 node-halves per thread, shfl-reduce over octet
    {
        int q = t & 7;
#pragma unroll
        for (int half = 0; half < 2; ++half) {
            int vl = (t >> 3) + half * 32;
            int v = base + vl;
            int start = sh_start[vl], len = sh_len[vl];
            float a0 = 0.f, a1 = 0.f, a2 = 0.f, a3 = 0.f, a4 = 0.f;
            if (q == 0 && v < n) {
                uint4 r = *(const uint4*)(xs + (size_t)v * 8);
                const __half2* h = (const __half2*)&r;
                float2 f0 = __half22float2(h[0]), f1 = __half22float2(h[1]), f2 = __half22float2(h[2]);
                a0 = f0.x; a1 = f0.y; a2 = f1.x; a3 = f1.y; a4 = f2.x;
            }
            for (int k = q; k < len; k += 8) {
                int s = col[start + k];
                uint4 r = *(const uint4*)(xs + (size_t)s * 8);
                const __half2* h = (const __half2*)&r;
                float2 f0 = __half22float2(h[0]), f1 = __half22float2(h[1]), f2 = __half22float2(h[2]);
                a0 += f0.x; a1 += f0.y; a2 += f1.x; a3 += f1.y; a4 += f2.x;
            }
#pragma unroll
            for (int d = 1; d <= 4; d <<= 1) {
                a0 += __shfl_down(a0, d, 64);
                a1 += __shfl_down(a1, d, 64);
                a2 += __shfl_down(a2, d, 64);
                a3 += __shfl_down(a3, d, 64);
                a4 += __shfl_down(a4, d, 64);
            }
            if (q == 0) {
                float* sx = sh_xa + vl * 9;
                sx[0] = a0; sx[1] = a1; sx[2] = a2; sx[3] = a3; sx[4] = a4;
            }
        }
    }
    __syncthreads();

    // Phase A: h1[j][v] = relu(dinv[v]*dot(xa[v],W1[:,j]) + b1[j]), fp16 store
    for (int p = 0; p < 32; ++p) {
        int idx = p * 256 + t;
        int v = idx & 63;
        int j = idx >> 6;
        const float* xa = sh_xa + v * 9;
        float acc = 0.f;
#pragma unroll
        for (int k = 0; k < IN_C; ++k)
            acc += xa[k] * W1[k * HID + j];
        sh_h1[j * NB + v] = __float2half(fmaxf(acc * sh_dinv[v] + b1[j], 0.f));
    }
    __syncthreads();

    // Phase B: g2[v][j] = dinv[v] * sum_k h1[k][v] * W2[k][j]
    int jt = t & 15;
    int vt = t >> 4;
    const __half* hp = sh_h1 + vt * 4;
    const float* wp = W2 + jt * 4;
    float4 a0 = make_float4(0.f, 0.f, 0.f, 0.f), a1 = a0, a2 = a0, a3 = a0;
#pragma unroll 4
    for (int k = 0; k < HID; ++k) {
        uint2 raw = *(const uint2*)(hp + k * NB);
        const __half2* hh = (const __half2*)&raw;
        float2 lo = __half22float2(hh[0]), hi = __half22float2(hh[1]);
        float4 w4 = *(const float4*)(wp + k * OUTC);
        a0.x += lo.x * w4.x; a0.y += lo.x * w4.y; a0.z += lo.x * w4.z; a0.w += lo.x * w4.w;
        a1.x += lo.y * w4.x; a1.y += lo.y * w4.y; a1.z += lo.y * w4.z; a1.w += lo.y * w4.w;
        a2.x += hi.x * w4.x; a2.y += hi.x * w4.y; a2.z += hi.x * w4.z; a2.w += hi.x * w4.w;
        a3.x += hi.y * w4.x; a3.y += hi.y * w4.y; a3.z += hi.y * w4.z; a3.w += hi.y * w4.w;
    }
    float4 accs[4] = {a0, a1, a2, a3};
#pragma unroll
    for (int a = 0; a < 4; ++a) {
        int vl = vt * 4 + a;
        int v = base + vl;
        if (v < n) {
            float dv = sh_dinv[vl];
            __half2 h[2];
            h[0] = __floats2half2_rn(accs[a].x * dv, accs[a].y * dv);
            h[1] = __floats2half2_rn(accs[a].z * dv, accs[a].w * dv);
            *(uint2*)(g2 + (size_t)v * OUTC + jt * 4) = *(uint2*)h;
        }
    }
}

// ---------------- layer 2 aggregation: 16 rows in flight per wave ----------------
__global__ void __launch_bounds__(256)
k_agg2(const __half* __restrict__ g2, const float* __restrict__ dinv,
       const int* __restrict__ rowptr, const int* __restrict__ cnt,
       const int* __restrict__ col, const float* __restrict__ b2,
       float* __restrict__ out, int n) {
    int t = threadIdx.x;
    int v = blockIdx.x * 4 + (t >> 6);   // wave-uniform
    if (v >= n) return;
    int lane = t & 63;
    int slot = lane >> 3;    // 0..7 neighbor slot
    int oct  = lane & 7;     // 0..7 feature octet (8 halves = 16B)
    int start = rowptr[v], len = cnt[v];
    float a0 = 0.f, a1 = 0.f, a2 = 0.f, a3 = 0.f, a4 = 0.f, a5 = 0.f, a6 = 0.f, a7 = 0.f;
    int it = slot;
    for (; it + 8 < len; it += 16) {
        int s0 = col[start + it];
        int s1 = col[start + it + 8];
        uint4 r0 = *(const uint4*)(g2 + (size_t)s0 * OUTC + oct * 8);
        uint4 r1 = *(const uint4*)(g2 + (size_t)s1 * OUTC + oct * 8);
        const __half2* h0 = (const __half2*)&r0;
        const __half2* h1 = (const __half2*)&r1;
        float2 f0 = __half22float2(h0[0]), f1 = __half22float2(h0[1]);
        float2 f2 = __half22float2(h0[2]), f3 = __half22float2(h0[3]);
        float2 g0 = __half22float2(h1[0]), g1 = __half22float2(h1[1]);
        float2 g2v = __half22float2(h1[2]), g3 = __half22float2(h1[3]);
        a0 += f0.x + g0.x; a1 += f0.y + g0.y; a2 += f1.x + g1.x; a3 += f1.y + g1.y;
        a4 += f2.x + g2v.x; a5 += f2.y + g2v.y; a6 += f3.x + g3.x; a7 += f3.y + g3.y;
    }
    for (; it < len; it += 8) {
        int s = col[start + it];
        uint4 raw = *(const uint4*)(g2 + (size_t)s * OUTC + oct * 8);
        const __half2* h = (const __half2*)&raw;
        float2 f0 = __half22float2(h[0]), f1 = __half22float2(h[1]);
        float2 f2 = __half22float2(h[2]), f3 = __half22float2(h[3]);
        a0 += f0.x; a1 += f0.y; a2 += f1.x; a3 += f1.y;
        a4 += f2.x; a5 += f2.y; a6 += f3.x; a7 += f3.y;
    }
#pragma unroll
    for (int d = 8; d <= 32; d <<= 1) {
        a0 += __shfl_down(a0, d, 64); a1 += __shfl_down(a1, d, 64);
        a2 += __shfl_down(a2, d, 64); a3 += __shfl_down(a3, d, 64);
        a4 += __shfl_down(a4, d, 64); a5 += __shfl_down(a5, d, 64);
        a6 += __shfl_down(a6, d, 64); a7 += __shfl_down(a7, d, 64);
    }
    if (lane < 8) {
        uint4 raw = *(const uint4*)(g2 + (size_t)v * OUTC + oct * 8);
        const __half2* h = (const __half2*)&raw;
        float2 s0 = __half22float2(h[0]), s1 = __half22float2(h[1]);
        float2 s2 = __half22float2(h[2]), s3 = __half22float2(h[3]);
        const float4* bp = (const float4*)(b2 + oct * 8);
        float4 bb0 = bp[0], bb1 = bp[1];
        float dv = dinv[v];
        float4 o0 = make_float4(dv * (a0 + s0.x) + bb0.x,
                                dv * (a1 + s0.y) + bb0.y,
                                dv * (a2 + s1.x) + bb0.z,
                                dv * (a3 + s1.y) + bb0.w);
        float4 o1 = make_float4(dv * (a4 + s2.x) + bb1.x,
                                dv * (a5 + s2.y) + bb1.y,
                                dv * (a6 + s3.x) + bb1.z,
                                dv * (a7 + s3.y) + bb1.w);
        float4* op = (float4*)(out + (size_t)v * OUTC + oct * 8);
        op[0] = o0; op[1] = o1;
    }
}

// ---------------- launch ----------------

extern "C" void kernel_launch(void* const* d_in, const int* in_sizes, int n_in,
                              void* d_out, int out_size, void* d_ws, size_t ws_size,
                              hipStream_t stream) {
    const float* x  = (const float*)d_in[0];
    const int*   ei = (const int*)d_in[1];
    const float* W1 = (const float*)d_in[2];
    const float* b1 = (const float*)d_in[3];
    const float* W2 = (const float*)d_in[4];
    const float* b2 = (const float*)d_in[5];
    float*       out = (float*)d_out;

    const int n = in_sizes[0] / IN_C;   // 100000
    const int E = in_sizes[1] / 2;      // 1600000
    const int* src = ei;
    const int* dst = ei + E;
    const int nbuck = (n + 511) / 512;  // 196

    char* ws = (char*)d_ws;
    size_t off = 0;
    int* cnt         = (int*)(ws + off); off += (size_t)n * 4;
    int* rowptr      = (int*)(ws + off); off += (size_t)n * 4;
    int* col         = (int*)(ws + off); off += (size_t)E * 4;
    float* dinv      = (float*)(ws + off); off += (size_t)n * 4;
    __half* xs       = (__half*)(ws + off); off += (size_t)n * 8 * 2;
    __half* g2       = (__half*)(ws + off); off += (size_t)n * OUTC * 2;
    int* bucket_cnt  = (int*)(ws + off); off += NBUCK_MAX * 4;
    int* bucket_base = (int*)(ws + off); off += NBUCK_MAX * 4;
    unsigned* binned = (unsigned*)(ws + off); off += (size_t)NBUCK_MAX * BCAP * 4;

    const int B = 256;

    hipMemsetAsync(bucket_cnt, 0, NBUCK_MAX * 4, stream);
    k_bin<<<256, B, 0, stream>>>(src, dst, bucket_cnt, binned, E);
    k_bucket_scan<<<1, 64, 0, stream>>>(bucket_cnt, bucket_base, nbuck);
    k_csr<<<nbuck, B, 0, stream>>>(binned, bucket_cnt, bucket_base, x,
                                   rowptr, cnt, dinv, xs, col, n);

    k_fused<<<(n + NB - 1) / NB, B, 0, stream>>>(xs, dinv, rowptr, cnt, col,
                                                 W1, b1, W2, g2, n);
    k_agg2<<<(n + 3) / 4, B, 0, stream>>>(g2, dinv, rowptr, cnt, col, b2, out, n);
}

// Round 8
// 215.803 us; speedup vs baseline: 5.2304x; 1.0475x over previous
//
#include <hip/hip_runtime.h>
#include <hip/hip_fp16.h>

#define IN_C 5
#define HID  128
#define OUTC 64

#define NBUCK_MAX 256     // buckets = ceil(n/512); n=100000 -> 196
#define BCAP      12288   // per-bucket region capacity (mean 8192, sigma ~90)

typedef _Float16 f16x8 __attribute__((ext_vector_type(8)));
typedef float    f32x4 __attribute__((ext_vector_type(4)));

// ---------------- CSR build: 2-pass LDS counting sort ----------------

__global__ void __launch_bounds__(256)
k_bin(const int* __restrict__ src, const int* __restrict__ dst,
      int* __restrict__ bucket_cnt, unsigned* __restrict__ binned, int E) {
    __shared__ int hist[NBUCK_MAX], base[NBUCK_MAX], cur[NBUCK_MAX];
    int t = threadIdx.x;
    for (int i = t; i < NBUCK_MAX; i += 256) { hist[i] = 0; cur[i] = 0; }
    __syncthreads();
    int per = (E + gridDim.x - 1) / gridDim.x;
    int lo = blockIdx.x * per, hi = min(E, lo + per);
    for (int e = lo + t; e < hi; e += 256)
        atomicAdd(&hist[dst[e] >> 9], 1);
    __syncthreads();
    for (int i = t; i < NBUCK_MAX; i += 256)
        if (hist[i] > 0) base[i] = atomicAdd(&bucket_cnt[i], hist[i]);
    __syncthreads();
    for (int e = lo + t; e < hi; e += 256) {
        int d = dst[e];
        int b = d >> 9;
        unsigned p = ((unsigned)src[e] << 9) | (unsigned)(d & 511);
        int r = atomicAdd(&cur[b], 1);
        binned[(size_t)b * BCAP + base[b] + r] = p;
    }
}

__global__ void k_bucket_scan(const int* __restrict__ bucket_cnt,
                              int* __restrict__ bucket_base, int nb) {
    if (threadIdx.x == 0 && blockIdx.x == 0) {
        int acc = 0;
        for (int i = 0; i < nb; ++i) { bucket_base[i] = acc; acc += bucket_cnt[i]; }
    }
}

// W2 (128x64 f32) -> fp16 in MFMA B-fragment order:
// flat = ((nt*4+kk)*64 + lane)*8 + j  holds  B[k=kk*32+(lane>>4)*8+j][n=nt*16+(lane&15)]
__global__ void __launch_bounds__(256)
k_packW2(const float* __restrict__ W2, __half* __restrict__ W2p) {
    int i = blockIdx.x * 256 + threadIdx.x;   // 8192
    int j = i & 7;
    int lane = (i >> 3) & 63;
    int kk = (i >> 9) & 3;
    int nt = i >> 11;
    int k = kk * 32 + (lane >> 4) * 8 + j;
    int nn = nt * 16 + (lane & 15);
    W2p[i] = __float2half(W2[k * OUTC + nn]);
}

// Pass B: one block per bucket (512 nodes). Also emits xs as fp16[8] per node.
__global__ void __launch_bounds__(256)
k_csr(const unsigned* __restrict__ binned, const int* __restrict__ bucket_cnt,
      const int* __restrict__ bucket_base, const float* __restrict__ x,
      int* __restrict__ rowptr, int* __restrict__ cnt, float* __restrict__ dinv,
      __half* __restrict__ xs, int* __restrict__ col, int n) {
    __shared__ int hist[512], rstart[512], cur[512];
    __shared__ int chunk_tot[8], chunk_off[8];
    int b = blockIdx.x;
    int t = threadIdx.x;
    int m = bucket_cnt[b];
    int ebase = bucket_base[b];
    const unsigned* bin = binned + (size_t)b * BCAP;

    for (int i = t; i < 512; i += 256) hist[i] = 0;
    __syncthreads();
    for (int e = t; e < m; e += 256)
        atomicAdd(&hist[bin[e] & 511], 1);
    __syncthreads();
    if (t < 8) {
        int acc = 0;
        for (int i = 0; i < 64; ++i) { int idx = t * 64 + i; rstart[idx] = acc; acc += hist[idx]; }
        chunk_tot[t] = acc;
    }
    __syncthreads();
    if (t == 0) {
        int acc = 0;
        for (int i = 0; i < 8; ++i) { chunk_off[i] = acc; acc += chunk_tot[i]; }
    }
    __syncthreads();
    for (int i = t; i < 512; i += 256) {
        int rs = rstart[i] + chunk_off[i >> 6];
        cur[i] = rs;
        int v = b * 512 + i;
        if (v < n) {
            rowptr[v] = ebase + rs;
            int c = hist[i];
            cnt[v] = c;
            float dv = rsqrtf(1.0f + (float)c);
            dinv[v] = dv;
            const float* xp = x + (size_t)v * IN_C;
            __half2 h[4];
            h[0] = __floats2half2_rn(xp[0] * dv, xp[1] * dv);
            h[1] = __floats2half2_rn(xp[2] * dv, xp[3] * dv);
            h[2] = __floats2half2_rn(xp[4] * dv, 0.f);
            h[3] = __floats2half2_rn(0.f, 0.f);
            *(uint4*)(xs + (size_t)v * 8) = *(uint4*)h;
        }
    }
    __syncthreads();
    for (int e = t; e < m; e += 256) {
        unsigned p = bin[e];
        int pos = atomicAdd(&cur[p & 511], 1);
        col[ebase + pos] = (int)(p >> 9);
    }
}

// ------- fused: layer-1 gather + gemm1+relu (VALU) + gemm2 (MFMA fp16) -------
#define NB 64
#define H1STRIDE 136   // 128 + 8 halves pad: conflict-free A-frag b128 reads
__global__ void __launch_bounds__(256, 6)
k_fused(const __half* __restrict__ xs, const float* __restrict__ dinv,
        const int* __restrict__ rowptr, const int* __restrict__ cnt,
        const int* __restrict__ col,
        const float* __restrict__ W1, const float* __restrict__ b1,
        const __half* __restrict__ W2p, __half* __restrict__ g2, int n) {
    __shared__ __half sh_h1[NB * H1STRIDE];   // 17408 B, [node][k]
    __shared__ float sh_xa[NB * 9];
    __shared__ float sh_dinv[NB];
    __shared__ int sh_start[NB], sh_len[NB];
    int t = threadIdx.x;
    int base = blockIdx.x * NB;

    if (t < NB) {
        int v = base + t;
        if (v < n) {
            sh_start[t] = rowptr[v];
            sh_len[t]   = cnt[v];
            sh_dinv[t]  = dinv[v];
        } else {
            sh_start[t] = 0; sh_len[t] = 0; sh_dinv[t] = 0.f;
        }
    }
    __syncthreads();

    // Gather: 8 threads per node, 2 node-halves per thread, shfl-reduce over octet
    {
        int q = t & 7;
#pragma unroll
        for (int half = 0; half < 2; ++half) {
            int vl = (t >> 3) + half * 32;
            int v = base + vl;
            int start = sh_start[vl], len = sh_len[vl];
            float a0 = 0.f, a1 = 0.f, a2 = 0.f, a3 = 0.f, a4 = 0.f;
            if (q == 0 && v < n) {
                uint4 r = *(const uint4*)(xs + (size_t)v * 8);
                const __half2* h = (const __half2*)&r;
                float2 f0 = __half22float2(h[0]), f1 = __half22float2(h[1]), f2 = __half22float2(h[2]);
                a0 = f0.x; a1 = f0.y; a2 = f1.x; a3 = f1.y; a4 = f2.x;
            }
            for (int k = q; k < len; k += 8) {
                int s = col[start + k];
                uint4 r = *(const uint4*)(xs + (size_t)s * 8);
                const __half2* h = (const __half2*)&r;
                float2 f0 = __half22float2(h[0]), f1 = __half22float2(h[1]), f2 = __half22float2(h[2]);
                a0 += f0.x; a1 += f0.y; a2 += f1.x; a3 += f1.y; a4 += f2.x;
            }
#pragma unroll
            for (int d = 1; d <= 4; d <<= 1) {
                a0 += __shfl_down(a0, d, 64);
                a1 += __shfl_down(a1, d, 64);
                a2 += __shfl_down(a2, d, 64);
                a3 += __shfl_down(a3, d, 64);
                a4 += __shfl_down(a4, d, 64);
            }
            if (q == 0) {
                float* sx = sh_xa + vl * 9;
                sx[0] = a0; sx[1] = a1; sx[2] = a2; sx[3] = a3; sx[4] = a4;
            }
        }
    }
    __syncthreads();

    // Phase A (VALU): h1[v][j] = relu(dinv[v]*dot(xa[v],W1[:,j]) + b1[j]), fp16.
    // thread t: v = t>>2, handles j-pairs jp = (t&3)+4i (i=0..15) -> bank-rotating writes
    {
        int v = t >> 2;
        const float* xa = sh_xa + v * 9;
        float x0 = xa[0], x1 = xa[1], x2 = xa[2], x3 = xa[3], x4 = xa[4];
        float dv = sh_dinv[v];
        __half* hrow = sh_h1 + v * H1STRIDE;
#pragma unroll
        for (int i = 0; i < 16; ++i) {
            int jp = (t & 3) + 4 * i;
            int j0 = jp * 2;
            float acc0 = 0.f, acc1 = 0.f;
#pragma unroll
            for (int k = 0; k < IN_C; ++k) {
                float2 w2 = *(const float2*)(W1 + k * HID + j0);
                float xv = (k == 0) ? x0 : (k == 1) ? x1 : (k == 2) ? x2 : (k == 3) ? x3 : x4;
                acc0 += xv * w2.x;
                acc1 += xv * w2.y;
            }
            float2 bb = *(const float2*)(b1 + j0);
            *(__half2*)(hrow + j0) =
                __floats2half2_rn(fmaxf(acc0 * dv + bb.x, 0.f), fmaxf(acc1 * dv + bb.y, 0.f));
        }
    }
    __syncthreads();

    // Phase B (MFMA): g2[v][j] = dinv[v] * (h1 @ W2)[v][j]
    // wave w: m-tile = nodes 16w..16w+15. A[m=lane&15][k=quad*8+j] from sh_h1.
    {
        int w = t >> 6;
        int lane = t & 63;
        int quad = lane >> 4, nn = lane & 15;
        const __half* arow = sh_h1 + (size_t)(w * 16 + nn) * H1STRIDE + quad * 8;
        f16x8 afr[4];
#pragma unroll
        for (int kk = 0; kk < 4; ++kk)
            afr[kk] = *(const f16x8*)(arow + kk * 32);

        const f16x8* bp = (const f16x8*)W2p + lane;
#pragma unroll
        for (int nt = 0; nt < 4; ++nt) {
            f32x4 acc = {0.f, 0.f, 0.f, 0.f};
#pragma unroll
            for (int kk = 0; kk < 4; ++kk)
                acc = __builtin_amdgcn_mfma_f32_16x16x32_f16(
                    afr[kk], bp[(nt * 4 + kk) * 64], acc, 0, 0, 0);
#pragma unroll
            for (int r = 0; r < 4; ++r) {
                int vl = w * 16 + quad * 4 + r;
                int v = base + vl;
                if (v < n)
                    g2[(size_t)v * OUTC + nt * 16 + nn] =
                        __float2half(acc[r] * sh_dinv[vl]);
            }
        }
    }
}

// ---------------- layer 2 aggregation: 16 rows in flight per wave ----------------
__global__ void __launch_bounds__(256)
k_agg2(const __half* __restrict__ g2, const float* __restrict__ dinv,
       const int* __restrict__ rowptr, const int* __restrict__ cnt,
       const int* __restrict__ col, const float* __restrict__ b2,
       float* __restrict__ out, int n) {
    int t = threadIdx.x;
    int v = blockIdx.x * 4 + (t >> 6);   // wave-uniform
    if (v >= n) return;
    int lane = t & 63;
    int slot = lane >> 3;    // 0..7 neighbor slot
    int oct  = lane & 7;     // 0..7 feature octet (8 halves = 16B)
    int start = rowptr[v], len = cnt[v];
    float a0 = 0.f, a1 = 0.f, a2 = 0.f, a3 = 0.f, a4 = 0.f, a5 = 0.f, a6 = 0.f, a7 = 0.f;
    int it = slot;
    for (; it + 8 < len; it += 16) {
        int s0 = col[start + it];
        int s1 = col[start + it + 8];
        uint4 r0 = *(const uint4*)(g2 + (size_t)s0 * OUTC + oct * 8);
        uint4 r1 = *(const uint4*)(g2 + (size_t)s1 * OUTC + oct * 8);
        const __half2* h0 = (const __half2*)&r0;
        const __half2* h1 = (const __half2*)&r1;
        float2 f0 = __half22float2(h0[0]), f1 = __half22float2(h0[1]);
        float2 f2 = __half22float2(h0[2]), f3 = __half22float2(h0[3]);
        float2 g0 = __half22float2(h1[0]), g1 = __half22float2(h1[1]);
        float2 g2v = __half22float2(h1[2]), g3 = __half22float2(h1[3]);
        a0 += f0.x + g0.x; a1 += f0.y + g0.y; a2 += f1.x + g1.x; a3 += f1.y + g1.y;
        a4 += f2.x + g2v.x; a5 += f2.y + g2v.y; a6 += f3.x + g3.x; a7 += f3.y + g3.y;
    }
    for (; it < len; it += 8) {
        int s = col[start + it];
        uint4 raw = *(const uint4*)(g2 + (size_t)s * OUTC + oct * 8);
        const __half2* h = (const __half2*)&raw;
        float2 f0 = __half22float2(h[0]), f1 = __half22float2(h[1]);
        float2 f2 = __half22float2(h[2]), f3 = __half22float2(h[3]);
        a0 += f0.x; a1 += f0.y; a2 += f1.x; a3 += f1.y;
        a4 += f2.x; a5 += f2.y; a6 += f3.x; a7 += f3.y;
    }
#pragma unroll
    for (int d = 8; d <= 32; d <<= 1) {
        a0 += __shfl_down(a0, d, 64); a1 += __shfl_down(a1, d, 64);
        a2 += __shfl_down(a2, d, 64); a3 += __shfl_down(a3, d, 64);
        a4 += __shfl_down(a4, d, 64); a5 += __shfl_down(a5, d, 64);
        a6 += __shfl_down(a6, d, 64); a7 += __shfl_down(a7, d, 64);
    }
    if (lane < 8) {
        uint4 raw = *(const uint4*)(g2 + (size_t)v * OUTC + oct * 8);
        const __half2* h = (const __half2*)&raw;
        float2 s0 = __half22float2(h[0]), s1 = __half22float2(h[1]);
        float2 s2 = __half22float2(h[2]), s3 = __half22float2(h[3]);
        const float4* bp = (const float4*)(b2 + oct * 8);
        float4 bb0 = bp[0], bb1 = bp[1];
        float dv = dinv[v];
        float4 o0 = make_float4(dv * (a0 + s0.x) + bb0.x,
                                dv * (a1 + s0.y) + bb0.y,
                                dv * (a2 + s1.x) + bb0.z,
                                dv * (a3 + s1.y) + bb0.w);
        float4 o1 = make_float4(dv * (a4 + s2.x) + bb1.x,
                                dv * (a5 + s2.y) + bb1.y,
                                dv * (a6 + s3.x) + bb1.z,
                                dv * (a7 + s3.y) + bb1.w);
        float4* op = (float4*)(out + (size_t)v * OUTC + oct * 8);
        op[0] = o0; op[1] = o1;
    }
}

// ---------------- launch ----------------

extern "C" void kernel_launch(void* const* d_in, const int* in_sizes, int n_in,
                              void* d_out, int out_size, void* d_ws, size_t ws_size,
                              hipStream_t stream) {
    const float* x  = (const float*)d_in[0];
    const int*   ei = (const int*)d_in[1];
    const float* W1 = (const float*)d_in[2];
    const float* b1 = (const float*)d_in[3];
    const float* W2 = (const float*)d_in[4];
    const float* b2 = (const float*)d_in[5];
    float*       out = (float*)d_out;

    const int n = in_sizes[0] / IN_C;   // 100000
    const int E = in_sizes[1] / 2;      // 1600000
    const int* src = ei;
    const int* dst = ei + E;
    const int nbuck = (n + 511) / 512;  // 196

    char* ws = (char*)d_ws;
    size_t off = 0;
    int* cnt         = (int*)(ws + off); off += (size_t)n * 4;
    int* rowptr      = (int*)(ws + off); off += (size_t)n * 4;
    int* col         = (int*)(ws + off); off += (size_t)E * 4;
    float* dinv      = (float*)(ws + off); off += (size_t)n * 4;
    __half* xs       = (__half*)(ws + off); off += (size_t)n * 8 * 2;
    __half* g2       = (__half*)(ws + off); off += (size_t)n * OUTC * 2;
    __half* W2p      = (__half*)(ws + off); off += (size_t)HID * OUTC * 2;
    int* bucket_cnt  = (int*)(ws + off); off += NBUCK_MAX * 4;
    int* bucket_base = (int*)(ws + off); off += NBUCK_MAX * 4;
    unsigned* binned = (unsigned*)(ws + off); off += (size_t)NBUCK_MAX * BCAP * 4;

    const int B = 256;

    hipMemsetAsync(bucket_cnt, 0, NBUCK_MAX * 4, stream);
    k_packW2<<<(HID * OUTC) / B, B, 0, stream>>>(W2, W2p);
    k_bin<<<512, B, 0, stream>>>(src, dst, bucket_cnt, binned, E);
    k_bucket_scan<<<1, 64, 0, stream>>>(bucket_cnt, bucket_base, nbuck);
    k_csr<<<nbuck, B, 0, stream>>>(binned, bucket_cnt, bucket_base, x,
                                   rowptr, cnt, dinv, xs, col, n);

    k_fused<<<(n + NB - 1) / NB, B, 0, stream>>>(xs, dinv, rowptr, cnt, col,
                                                 W1, b1, W2p, g2, n);
    k_agg2<<<(n + 3) / 4, B, 0, stream>>>(g2, dinv, rowptr, cnt, col, b2, out, n);
}

// Round 9
// 201.835 us; speedup vs baseline: 5.5924x; 1.0692x over previous
//
#include <hip/hip_runtime.h>
#include <hip/hip_fp16.h>

#define IN_C 5
#define HID  128
#define OUTC 64

#define NBUCK_MAX 256     // buckets = ceil(n/512); n=100000 -> 196
#define BCAP      12288   // per-bucket region capacity (mean 8192, sigma ~90)

typedef _Float16 f16x8 __attribute__((ext_vector_type(8)));
typedef float    f32x4 __attribute__((ext_vector_type(4)));

// ---------------- init: zero bucket counters + pack W2 for MFMA ----------------
// W2 (128x64 f32) -> fp16 in MFMA B-fragment order:
// flat = ((nt*4+kk)*64 + lane)*8 + j  holds  B[k=kk*32+(lane>>4)*8+j][n=nt*16+(lane&15)]
__global__ void __launch_bounds__(256)
k_init(const float* __restrict__ W2, __half* __restrict__ W2p,
       int* __restrict__ bucket_cnt) {
    if (blockIdx.x == 0) bucket_cnt[threadIdx.x] = 0;
    int i = blockIdx.x * 256 + threadIdx.x;   // 8192
    int j = i & 7;
    int lane = (i >> 3) & 63;
    int kk = (i >> 9) & 3;
    int nt = i >> 11;
    int k = kk * 32 + (lane >> 4) * 8 + j;
    int nn = nt * 16 + (lane & 15);
    W2p[i] = __float2half(W2[k * OUTC + nn]);
}

// ---------------- CSR build: 2-pass LDS counting sort ----------------

__global__ void __launch_bounds__(256)
k_bin(const int* __restrict__ src, const int* __restrict__ dst,
      int* __restrict__ bucket_cnt, unsigned* __restrict__ binned, int E) {
    __shared__ int hist[NBUCK_MAX], base[NBUCK_MAX], cur[NBUCK_MAX];
    int t = threadIdx.x;
    hist[t] = 0; cur[t] = 0;
    __syncthreads();
    int per = (E + gridDim.x - 1) / gridDim.x;
    int lo = blockIdx.x * per, hi = min(E, lo + per);
    for (int e = lo + t; e < hi; e += 256)
        atomicAdd(&hist[dst[e] >> 9], 1);
    __syncthreads();
    if (hist[t] > 0) base[t] = atomicAdd(&bucket_cnt[t], hist[t]);
    __syncthreads();
    for (int e = lo + t; e < hi; e += 256) {
        int d = dst[e];
        int b = d >> 9;
        unsigned p = ((unsigned)src[e] << 9) | (unsigned)(d & 511);
        int r = atomicAdd(&cur[b], 1);
        binned[(size_t)b * BCAP + base[b] + r] = p;
    }
}

// Pass B: one block per bucket (512 nodes). Computes its own exclusive-prefix
// base from bucket_cnt (256-wide LDS scan). Emits rowptr/cnt/dinv/xs/col.
__global__ void __launch_bounds__(256)
k_csr(const unsigned* __restrict__ binned, const int* __restrict__ bucket_cnt,
      const float* __restrict__ x,
      int* __restrict__ rowptr, int* __restrict__ cnt, float* __restrict__ dinv,
      __half* __restrict__ xs, int* __restrict__ col, int n) {
    __shared__ int hist[512], rstart[512], cur[512];
    __shared__ int chunk_tot[8], chunk_off[8];
    __shared__ int sc[NBUCK_MAX];
    int b = blockIdx.x;
    int t = threadIdx.x;

    // inclusive scan of bucket_cnt -> sc; ebase = sc[b-1]
    sc[t] = bucket_cnt[t];
    __syncthreads();
#pragma unroll
    for (int off = 1; off < NBUCK_MAX; off <<= 1) {
        int add = (t >= off) ? sc[t - off] : 0;
        __syncthreads();
        sc[t] += add;
        __syncthreads();
    }
    int m = bucket_cnt[b];
    int ebase = (b == 0) ? 0 : sc[b - 1];
    const unsigned* bin = binned + (size_t)b * BCAP;

    for (int i = t; i < 512; i += 256) hist[i] = 0;
    __syncthreads();
    for (int e = t; e < m; e += 256)
        atomicAdd(&hist[bin[e] & 511], 1);
    __syncthreads();
    if (t < 8) {
        int acc = 0;
        for (int i = 0; i < 64; ++i) { int idx = t * 64 + i; rstart[idx] = acc; acc += hist[idx]; }
        chunk_tot[t] = acc;
    }
    __syncthreads();
    if (t == 0) {
        int acc = 0;
        for (int i = 0; i < 8; ++i) { chunk_off[i] = acc; acc += chunk_tot[i]; }
    }
    __syncthreads();
    for (int i = t; i < 512; i += 256) {
        int rs = rstart[i] + chunk_off[i >> 6];
        cur[i] = rs;
        int v = b * 512 + i;
        if (v < n) {
            rowptr[v] = ebase + rs;
            int c = hist[i];
            cnt[v] = c;
            float dv = rsqrtf(1.0f + (float)c);
            dinv[v] = dv;
            const float* xp = x + (size_t)v * IN_C;
            __half2 h[4];
            h[0] = __floats2half2_rn(xp[0] * dv, xp[1] * dv);
            h[1] = __floats2half2_rn(xp[2] * dv, xp[3] * dv);
            h[2] = __floats2half2_rn(xp[4] * dv, 0.f);
            h[3] = __floats2half2_rn(0.f, 0.f);
            *(uint4*)(xs + (size_t)v * 8) = *(uint4*)h;
        }
    }
    __syncthreads();
    for (int e = t; e < m; e += 256) {
        unsigned p = bin[e];
        int pos = atomicAdd(&cur[p & 511], 1);
        col[ebase + pos] = (int)(p >> 9);
    }
}

// ------- fused: layer-1 gather + gemm1+relu (VALU) + gemm2 (MFMA fp16) -------
#define NB 64
#define H1STRIDE 136   // 128 + 8 halves pad: conflict-free A-frag b128 reads
__global__ void __launch_bounds__(256, 6)
k_fused(const __half* __restrict__ xs, const float* __restrict__ dinv,
        const int* __restrict__ rowptr, const int* __restrict__ cnt,
        const int* __restrict__ col,
        const float* __restrict__ W1, const float* __restrict__ b1,
        const __half* __restrict__ W2p, __half* __restrict__ g2, int n) {
    __shared__ __half sh_h1[NB * H1STRIDE];   // 17408 B, [node][k]
    __shared__ float sh_xa[NB * 9];
    __shared__ float sh_dinv[NB];
    __shared__ int sh_start[NB], sh_len[NB];
    int t = threadIdx.x;
    int base = blockIdx.x * NB;

    if (t < NB) {
        int v = base + t;
        if (v < n) {
            sh_start[t] = rowptr[v];
            sh_len[t]   = cnt[v];
            sh_dinv[t]  = dinv[v];
        } else {
            sh_start[t] = 0; sh_len[t] = 0; sh_dinv[t] = 0.f;
        }
    }
    __syncthreads();

    // Gather: 8 threads per node, 2 node-halves per thread, shfl-reduce over octet
    {
        int q = t & 7;
#pragma unroll
        for (int half = 0; half < 2; ++half) {
            int vl = (t >> 3) + half * 32;
            int v = base + vl;
            int start = sh_start[vl], len = sh_len[vl];
            float a0 = 0.f, a1 = 0.f, a2 = 0.f, a3 = 0.f, a4 = 0.f;
            if (q == 0 && v < n) {
                uint4 r = *(const uint4*)(xs + (size_t)v * 8);
                const __half2* h = (const __half2*)&r;
                float2 f0 = __half22float2(h[0]), f1 = __half22float2(h[1]), f2 = __half22float2(h[2]);
                a0 = f0.x; a1 = f0.y; a2 = f1.x; a3 = f1.y; a4 = f2.x;
            }
            for (int k = q; k < len; k += 8) {
                int s = col[start + k];
                uint4 r = *(const uint4*)(xs + (size_t)s * 8);
                const __half2* h = (const __half2*)&r;
                float2 f0 = __half22float2(h[0]), f1 = __half22float2(h[1]), f2 = __half22float2(h[2]);
                a0 += f0.x; a1 += f0.y; a2 += f1.x; a3 += f1.y; a4 += f2.x;
            }
#pragma unroll
            for (int d = 1; d <= 4; d <<= 1) {
                a0 += __shfl_down(a0, d, 64);
                a1 += __shfl_down(a1, d, 64);
                a2 += __shfl_down(a2, d, 64);
                a3 += __shfl_down(a3, d, 64);
                a4 += __shfl_down(a4, d, 64);
            }
            if (q == 0) {
                float* sx = sh_xa + vl * 9;
                sx[0] = a0; sx[1] = a1; sx[2] = a2; sx[3] = a3; sx[4] = a4;
            }
        }
    }
    __syncthreads();

    // Phase A (VALU): h1[v][j] = relu(dinv[v]*dot(xa[v],W1[:,j]) + b1[j]), fp16.
    {
        int v = t >> 2;
        const float* xa = sh_xa + v * 9;
        float x0 = xa[0], x1 = xa[1], x2 = xa[2], x3 = xa[3], x4 = xa[4];
        float dv = sh_dinv[v];
        __half* hrow = sh_h1 + v * H1STRIDE;
#pragma unroll
        for (int i = 0; i < 16; ++i) {
            int jp = (t & 3) + 4 * i;
            int j0 = jp * 2;
            float acc0 = 0.f, acc1 = 0.f;
#pragma unroll
            for (int k = 0; k < IN_C; ++k) {
                float2 w2 = *(const float2*)(W1 + k * HID + j0);
                float xv = (k == 0) ? x0 : (k == 1) ? x1 : (k == 2) ? x2 : (k == 3) ? x3 : x4;
                acc0 += xv * w2.x;
                acc1 += xv * w2.y;
            }
            float2 bb = *(const float2*)(b1 + j0);
            *(__half2*)(hrow + j0) =
                __floats2half2_rn(fmaxf(acc0 * dv + bb.x, 0.f), fmaxf(acc1 * dv + bb.y, 0.f));
        }
    }
    __syncthreads();

    // Phase B (MFMA): g2[v][j] = dinv[v] * (h1 @ W2)[v][j]
    {
        int w = t >> 6;
        int lane = t & 63;
        int quad = lane >> 4, nn = lane & 15;
        const __half* arow = sh_h1 + (size_t)(w * 16 + nn) * H1STRIDE + quad * 8;
        f16x8 afr[4];
#pragma unroll
        for (int kk = 0; kk < 4; ++kk)
            afr[kk] = *(const f16x8*)(arow + kk * 32);

        const f16x8* bp = (const f16x8*)W2p + lane;
#pragma unroll
        for (int nt = 0; nt < 4; ++nt) {
            f32x4 acc = {0.f, 0.f, 0.f, 0.f};
#pragma unroll
            for (int kk = 0; kk < 4; ++kk)
                acc = __builtin_amdgcn_mfma_f32_16x16x32_f16(
                    afr[kk], bp[(nt * 4 + kk) * 64], acc, 0, 0, 0);
#pragma unroll
            for (int r = 0; r < 4; ++r) {
                int vl = w * 16 + quad * 4 + r;
                int v = base + vl;
                if (v < n)
                    g2[(size_t)v * OUTC + nt * 16 + nn] =
                        __float2half(acc[r] * sh_dinv[vl]);
            }
        }
    }
}

// ---------------- layer 2 aggregation: 16 rows in flight per wave ----------------
__global__ void __launch_bounds__(256)
k_agg2(const __half* __restrict__ g2, const float* __restrict__ dinv,
       const int* __restrict__ rowptr, const int* __restrict__ cnt,
       const int* __restrict__ col, const float* __restrict__ b2,
       float* __restrict__ out, int n) {
    int t = threadIdx.x;
    int v = blockIdx.x * 4 + (t >> 6);   // wave-uniform
    if (v >= n) return;
    int lane = t & 63;
    int slot = lane >> 3;    // 0..7 neighbor slot
    int oct  = lane & 7;     // 0..7 feature octet (8 halves = 16B)
    int start = rowptr[v], len = cnt[v];
    float a0 = 0.f, a1 = 0.f, a2 = 0.f, a3 = 0.f, a4 = 0.f, a5 = 0.f, a6 = 0.f, a7 = 0.f;
    int it = slot;
    for (; it + 8 < len; it += 16) {
        int s0 = col[start + it];
        int s1 = col[start + it + 8];
        uint4 r0 = *(const uint4*)(g2 + (size_t)s0 * OUTC + oct * 8);
        uint4 r1 = *(const uint4*)(g2 + (size_t)s1 * OUTC + oct * 8);
        const __half2* h0 = (const __half2*)&r0;
        const __half2* h1 = (const __half2*)&r1;
        float2 f0 = __half22float2(h0[0]), f1 = __half22float2(h0[1]);
        float2 f2 = __half22float2(h0[2]), f3 = __half22float2(h0[3]);
        float2 g0 = __half22float2(h1[0]), g1 = __half22float2(h1[1]);
        float2 g2v = __half22float2(h1[2]), g3 = __half22float2(h1[3]);
        a0 += f0.x + g0.x; a1 += f0.y + g0.y; a2 += f1.x + g1.x; a3 += f1.y + g1.y;
        a4 += f2.x + g2v.x; a5 += f2.y + g2v.y; a6 += f3.x + g3.x; a7 += f3.y + g3.y;
    }
    for (; it < len; it += 8) {
        int s = col[start + it];
        uint4 raw = *(const uint4*)(g2 + (size_t)s * OUTC + oct * 8);
        const __half2* h = (const __half2*)&raw;
        float2 f0 = __half22float2(h[0]), f1 = __half22float2(h[1]);
        float2 f2 = __half22float2(h[2]), f3 = __half22float2(h[3]);
        a0 += f0.x; a1 += f0.y; a2 += f1.x; a3 += f1.y;
        a4 += f2.x; a5 += f2.y; a6 += f3.x; a7 += f3.y;
    }
#pragma unroll
    for (int d = 8; d <= 32; d <<= 1) {
        a0 += __shfl_down(a0, d, 64); a1 += __shfl_down(a1, d, 64);
        a2 += __shfl_down(a2, d, 64); a3 += __shfl_down(a3, d, 64);
        a4 += __shfl_down(a4, d, 64); a5 += __shfl_down(a5, d, 64);
        a6 += __shfl_down(a6, d, 64); a7 += __shfl_down(a7, d, 64);
    }
    if (lane < 8) {
        uint4 raw = *(const uint4*)(g2 + (size_t)v * OUTC + oct * 8);
        const __half2* h = (const __half2*)&raw;
        float2 s0 = __half22float2(h[0]), s1 = __half22float2(h[1]);
        float2 s2 = __half22float2(h[2]), s3 = __half22float2(h[3]);
        const float4* bp = (const float4*)(b2 + oct * 8);
        float4 bb0 = bp[0], bb1 = bp[1];
        float dv = dinv[v];
        float4 o0 = make_float4(dv * (a0 + s0.x) + bb0.x,
                                dv * (a1 + s0.y) + bb0.y,
                                dv * (a2 + s1.x) + bb0.z,
                                dv * (a3 + s1.y) + bb0.w);
        float4 o1 = make_float4(dv * (a4 + s2.x) + bb1.x,
                                dv * (a5 + s2.y) + bb1.y,
                                dv * (a6 + s3.x) + bb1.z,
                                dv * (a7 + s3.y) + bb1.w);
        float4* op = (float4*)(out + (size_t)v * OUTC + oct * 8);
        op[0] = o0; op[1] = o1;
    }
}

// ---------------- launch ----------------

extern "C" void kernel_launch(void* const* d_in, const int* in_sizes, int n_in,
                              void* d_out, int out_size, void* d_ws, size_t ws_size,
                              hipStream_t stream) {
    const float* x  = (const float*)d_in[0];
    const int*   ei = (const int*)d_in[1];
    const float* W1 = (const float*)d_in[2];
    const float* b1 = (const float*)d_in[3];
    const float* W2 = (const float*)d_in[4];
    const float* b2 = (const float*)d_in[5];
    float*       out = (float*)d_out;

    const int n = in_sizes[0] / IN_C;   // 100000
    const int E = in_sizes[1] / 2;      // 1600000
    const int* src = ei;
    const int* dst = ei + E;
    const int nbuck = (n + 511) / 512;  // 196

    char* ws = (char*)d_ws;
    size_t off = 0;
    int* cnt         = (int*)(ws + off); off += (size_t)n * 4;
    int* rowptr      = (int*)(ws + off); off += (size_t)n * 4;
    int* col         = (int*)(ws + off); off += (size_t)E * 4;
    float* dinv      = (float*)(ws + off); off += (size_t)n * 4;
    __half* xs       = (__half*)(ws + off); off += (size_t)n * 8 * 2;
    __half* g2       = (__half*)(ws + off); off += (size_t)n * OUTC * 2;
    __half* W2p      = (__half*)(ws + off); off += (size_t)HID * OUTC * 2;
    int* bucket_cnt  = (int*)(ws + off); off += NBUCK_MAX * 4;
    unsigned* binned = (unsigned*)(ws + off); off += (size_t)NBUCK_MAX * BCAP * 4;

    const int B = 256;

    k_init<<<(HID * OUTC) / B, B, 0, stream>>>(W2, W2p, bucket_cnt);
    k_bin<<<512, B, 0, stream>>>(src, dst, bucket_cnt, binned, E);
    k_csr<<<nbuck, B, 0, stream>>>(binned, bucket_cnt, x,
                                   rowptr, cnt, dinv, xs, col, n);

    k_fused<<<(n + NB - 1) / NB, B, 0, stream>>>(xs, dinv, rowptr, cnt, col,
                                                 W1, b1, W2p, g2, n);
    k_agg2<<<(n + 3) / 4, B, 0, stream>>>(g2, dinv, rowptr, cnt, col, b2, out, n);
}